// Round 9
// baseline (217.021 us; speedup 1.0000x reference)
//
#include <hip/hip_runtime.h>
#include <hip/hip_bf16.h>
#include <cmath>

// Problem constants (fixed by the reference)
constexpr int CB  = 8;     // batch
constexpr int CN  = 1024;  // sequence length
constexpr int CD  = 256;   // model dim
constexpr int CH  = 8;     // heads
constexpr int CDH = 32;    // head dim
constexpr int CR  = 4;     // relation types (adj value 4 = none)
constexpr int CFF = 1024;  // ffn dim
constexpr float CEPS = 1e-5f;
constexpr float CS = 0.25503480f;   // (1/sqrt(32)) * log2(e), folded into Q
constexpr size_t SZH = (size_t)CB * CH * CN * CDH;  // 2M: one head-plane

#define MODE_QK    0   // scatter bf16 q/k head-major planes, +bias (cols 0..511)
#define MODE_FFN1  2   // +bias, tanh-gelu -> bf16
#define MODE_VT    4   // V^T gemm (A=weight rows, B=src rows): sigma column store

typedef float v4f __attribute__((ext_vector_type(4)));
typedef short v8s __attribute__((ext_vector_type(8)));

static __device__ __forceinline__ short f2bf(float f) {
    unsigned u = __builtin_bit_cast(unsigned, f);
    u += 0x7fff + ((u >> 16) & 1);          // round-to-nearest-even
    return (short)(u >> 16);
}
static __device__ __forceinline__ float bf2f(short s) {
    unsigned u = ((unsigned)(unsigned short)s) << 16;
    return __builtin_bit_cast(float, u);
}
static __device__ __forceinline__ unsigned cvtpk_bf16(float lo, float hi) {
    unsigned r;
    asm("v_cvt_pk_bf16_f32 %0, %1, %2" : "=v"(r) : "v"(lo), "v"(hi));
    return r;
}

static __device__ __forceinline__ void async_copy16(const void* g, void* l) {
    __builtin_amdgcn_global_load_lds(
        (const __attribute__((address_space(1))) void*)g,
        (__attribute__((address_space(3))) void*)l, 16, 0, 0);
}

// PV k-order permutation sigma(j): c[5]=j[4], c[4:3]=j[3:2], c[2]=j[5],
// c[1:0]=j[1:0].  With swapped QK^T (sacc = mfma(K,Q)), lane (quad,l15)
// holds P[i=l15][j=16jb+4quad+rr], and sigma maps those 16 j's exactly onto
// PV A-operand k-slots {kb*32 + quad*8 + e} -> P never touches LDS.
// adjsel stores adj as BYTES in sigma pair order; at PV time the byte value
// itself is a v_perm selector into a one-hot 0xff table (v=4 -> zero operand).

// ---------------------------------------------------------------------------
// bf16 MFMA GEMM body (device fn, dynamic LDS): epilogue(A[M,K] @ Bw[N,K])
// BM x BN tile, 4 waves 2x2, BK=32 double-buffered 1-deep prefetch.
// ---------------------------------------------------------------------------
template<int BM, int BN, int MODE>
__device__ __forceinline__ void gemm_body(
    const short* __restrict__ A, const short* __restrict__ Bw,
    const float* __restrict__ biasv, void* __restrict__ dest,
    int M, int K, int Nw, int bx, int by, short* smem)
{
    constexpr int WTM = BM / 2, WTN = BN / 2;
    constexpr int TM = WTM / 16, TN = WTN / 16;
    short* As = smem;                    // [2][BM*32]
    short* Bs = smem + 2 * BM * 32;      // [2][BN*32]

    const int t    = threadIdx.x;
    const int lane = t & 63;
    const int w    = t >> 6;
    const int quad = lane >> 4, l15 = lane & 15;
    const int wm = w >> 1, wn = w & 1;
    const int m0 = bx * BM, n0 = by * BN;

    const int srow = lane >> 2;
    const int scol = (lane & 3) * 8;

    v4f acc[TM][TN];
    #pragma unroll
    for (int i = 0; i < TM; ++i)
        #pragma unroll
        for (int j = 0; j < TN; ++j) acc[i][j] = (v4f){0.f, 0.f, 0.f, 0.f};

    const int NK = K >> 5;

    auto stage = [&](int buf, int kt) {
        #pragma unroll
        for (int u = 0; u < BM / 64; ++u) {
            const int e0 = (w * (BM / 64) + u) * 512;
            const int row = (e0 >> 5) + srow;
            async_copy16(A + (size_t)(m0 + row) * K + kt + scol,
                         &As[buf * BM * 32 + e0]);
        }
        #pragma unroll
        for (int u = 0; u < BN / 64; ++u) {
            const int e0 = (w * (BN / 64) + u) * 512;
            const int row = (e0 >> 5) + srow;
            async_copy16(Bw + (size_t)(n0 + row) * K + kt + scol,
                         &Bs[buf * BN * 32 + e0]);
        }
    };

    stage(0, 0);

    for (int it = 0; it < NK; ++it) {
        __syncthreads();
        if (it + 1 < NK) stage((it + 1) & 1, (it + 1) << 5);

        const int buf = it & 1;
        v8s af[TM], bfr[TN];
        #pragma unroll
        for (int i = 0; i < TM; ++i)
            af[i] = *(const v8s*)&As[buf * BM * 32 +
                                     (wm * WTM + i * 16 + l15) * 32 + quad * 8];
        #pragma unroll
        for (int j = 0; j < TN; ++j)
            bfr[j] = *(const v8s*)&Bs[buf * BN * 32 +
                                      (wn * WTN + j * 16 + l15) * 32 + quad * 8];
        #pragma unroll
        for (int i = 0; i < TM; ++i)
            #pragma unroll
            for (int j = 0; j < TN; ++j)
                acc[i][j] = __builtin_amdgcn_mfma_f32_16x16x32_bf16(
                    af[i], bfr[j], acc[i][j], 0, 0, 0);
    }

    #pragma unroll
    for (int i = 0; i < TM; ++i) {
        #pragma unroll
        for (int j = 0; j < TN; ++j) {
            const int mb = m0 + wm * WTM + i * 16 + quad * 4;   // row of rr=0
            const int n  = n0 + wn * WTN + j * 16 + l15;
            float vals[4];
            if (MODE == MODE_VT) {
                #pragma unroll
                for (int rr = 0; rr < 4; ++rr) vals[rr] = acc[i][j][rr] + biasv[mb + rr];
            } else {
                #pragma unroll
                for (int rr = 0; rr < 4; ++rr) vals[rr] = acc[i][j][rr] + biasv[n];
            }

            if (MODE == MODE_QK) {
                // fold softmax scale into Q (q-plane blocks have n0 < 256)
                if (n0 < 256) {
                    #pragma unroll
                    for (int rr = 0; rr < 4; ++rr) vals[rr] *= CS;
                }
                const int b = mb >> 10, ii0 = mb & 1023;
                const int plane = n >> 8, nn = n & 255;
                const int h = nn >> 5, d = nn & 31;
                #pragma unroll
                for (int rr = 0; rr < 4; ++rr)
                    ((short*)dest)[(size_t)plane * SZH +
                        (((size_t)(b * CH + h)) * CN + ii0 + rr) * CDH + d] =
                        f2bf(vals[rr]);
            } else if (MODE == MODE_VT) {
                // sigma column permutation within each 64-token tile (see top)
                const int b = n >> 10, ii = n & 1023;
                const int jj = ii & 63;
                const int cc = (((jj >> 4) & 1) << 5) | (((jj >> 2) & 3) << 3) |
                               (((jj >> 5) & 1) << 2) | (jj & 3);
                const int iip = (ii & ~63) | cc;
                #pragma unroll
                for (int rr = 0; rr < 4; ++rr) {
                    const int m = mb + rr;
                    const int r2 = m >> 8, hd = m & 255;
                    const int h = hd >> 5, d = hd & 31;
                    ((short*)dest)[2 * SZH +
                        (((size_t)(r2 * 64 + b * CH + h)) * CDH + d) * CN + iip] =
                        f2bf(vals[rr]);
                }
            } else { // MODE_FFN1: tanh-gelu -> bf16 (x*E/(E+1))
                #pragma unroll
                for (int rr = 0; rr < 4; ++rr) {
                    const size_t idx = (size_t)(mb + rr) * Nw + n;
                    const float xx = vals[rr];
                    const float E = exp2f(2.302217f * (xx + 0.044715f * xx * xx * xx));
                    ((short*)dest)[idx] = f2bf(xx * E / (E + 1.f));
                }
            }
        }
    }
}

template<int BM, int BN, int MODE>
__global__ __launch_bounds__(256)
void gemm_mfma(const short* __restrict__ A, const short* __restrict__ Bw,
               const float* __restrict__ biasv, void* __restrict__ dest,
               int M, int K, int Nw)
{
    extern __shared__ short smem[];
    gemm_body<BM, BN, MODE>(A, Bw, biasv, dest, M, K, Nw,
                            blockIdx.x, blockIdx.y, smem);
}

// ---------------------------------------------------------------------------
// Fused projection dispatch (128x128 m97-style tiles):
//   blocks 0..255   = QK  (8192x512, K=256)
//   blocks 256..767 = V^T (1024x8192, K=256)
//   blocks 768..1279= adj int32 -> BYTE-pair pack in sigma order (adjsel)
// ---------------------------------------------------------------------------
__global__ __launch_bounds__(256)
void proj_kernel(const short* __restrict__ src_bf, const short* __restrict__ wqkvT,
                 const float* __restrict__ bpack, short* __restrict__ qkv,
                 const int* __restrict__ adj, unsigned char* __restrict__ adjsel)
{
    extern __shared__ short smem[];
    const int g = blockIdx.x;
    if (g < 256) {
        gemm_body<128, 128, MODE_QK>(src_bf, wqkvT, bpack, qkv,
                                     8192, 256, 512, g >> 2, g & 3, smem);
    } else if (g < 768) {
        const int h2 = g - 256;
        gemm_body<128, 128, MODE_VT>(wqkvT + 512 * 256, src_bf, bpack + 512,
                                     qkv, 1024, 256, 8192, h2 & 7, h2 >> 3, smem);
    } else {
        // sigma-order byte pack: int2 (row, dwi) holds adj bytes for the 8 j's
        // j0+{0..3}, j0+32+{0..3} with j0 = T*64 + (kq&3)*4 + (kq>>2)*16,
        // T = dwi>>3, kq = dwi&7  (kq = kb*4 + quad).
        const int nout = CB * CN * CN / 8;           // 1M int2 (8 j's each)
        for (int i = (g - 768) * 256 + threadIdx.x; i < nout; i += 512 * 256) {
            const int dwi = i & 127;
            const int row = i >> 7;
            const int T   = dwi >> 3, kq = dwi & 7;
            const int j0  = T * 64 + (kq & 3) * 4 + (kq >> 2) * 16;
            const int* p = adj + (size_t)row * CN + j0;
            const int4 q0 = *(const int4*)(p);
            const int4 q1 = *(const int4*)(p + 32);
            int2 o;
            o.x = (q0.x & 0xff) | ((q0.y & 0xff) << 8) |
                  ((q0.z & 0xff) << 16) | ((q0.w & 0xff) << 24);
            o.y = (q1.x & 0xff) | ((q1.y & 0xff) << 8) |
                  ((q1.z & 0xff) << 16) | ((q1.w & 0xff) << 24);
            ((int2*)adjsel)[i] = o;
        }
    }
}

// ---------------------------------------------------------------------------
// FUSED GEMM + bias + residual + LayerNorm, BM=16, BK=64 (half the barriers
// of BK=32; 8 MFMA per wave between barriers).  Granule-XOR swizzle on the
// 128B-stride LDS rows (source-side, linear dest) -> conflict-light reads.
// OUTF: write fp32 result; OUTB: write bf16 result; ADDBF: residual is bf16.
// ---------------------------------------------------------------------------
template<bool OUTF, bool OUTB, bool ADDBF>
__global__ __launch_bounds__(256)
void gemm_ln32(const short* __restrict__ A, const short* __restrict__ Bw,
               const float* __restrict__ biasv, const void* __restrict__ addp,
               const float* __restrict__ gw, const float* __restrict__ be,
               float* __restrict__ outf, short* __restrict__ outb, int K)
{
    __shared__ short As[2][16 * 64];
    __shared__ short Bs[2][256 * 64];
    __shared__ float redS[16][4], redQ[16][4];

    const int t    = threadIdx.x;
    const int lane = t & 63;
    const int w    = t >> 6;          // wave -> column quarter (64 cols)
    const int quad = lane >> 4, l15 = lane & 15;
    const int m0   = blockIdx.x * 16;
    const int xsw  = l15 & 7;         // read-side granule XOR

    v4f acc[4];
    #pragma unroll
    for (int j = 0; j < 4; ++j) acc[j] = (v4f){0.f, 0.f, 0.f, 0.f};

    const int NK = K >> 6;

    auto stage = [&](int buf, int kt) {
        if (t < 128) {   // A: 16 rows x 64 cols = 128 granules
            const int row = t >> 3, gc = t & 7;
            async_copy16(A + (size_t)(m0 + row) * K + kt + ((gc ^ (row & 7)) * 8),
                         &As[buf][t * 8]);
        }
        #pragma unroll
        for (int u = 0; u < 8; ++u) {   // B: 256 rows x 64 cols = 2048 granules
            const int gl = t + 256 * u;
            const int row = gl >> 3, gc = gl & 7;
            async_copy16(Bw + (size_t)row * K + kt + ((gc ^ (row & 7)) * 8),
                         &Bs[buf][gl * 8]);
        }
    };

    stage(0, 0);

    for (int it = 0; it < NK; ++it) {
        __syncthreads();
        if (it + 1 < NK) stage((it + 1) & 1, (it + 1) << 6);

        const int buf = it & 1;
        #pragma unroll
        for (int half = 0; half < 2; ++half) {
            const int gr = (quad + 4 * half) ^ xsw;
            const v8s af = *(const v8s*)&As[buf][l15 * 64 + gr * 8];
            #pragma unroll
            for (int j = 0; j < 4; ++j) {
                const v8s bfr = *(const v8s*)&Bs[buf][(w * 64 + 16 * j + l15) * 64 + gr * 8];
                acc[j] = __builtin_amdgcn_mfma_f32_16x16x32_bf16(af, bfr, acc[j], 0, 0, 0);
            }
        }
    }

    float v[4][4];
    #pragma unroll
    for (int rr = 0; rr < 4; ++rr) {
        const int row = m0 + quad * 4 + rr;
        float s = 0.f, sq = 0.f;
        #pragma unroll
        for (int j = 0; j < 4; ++j) {
            const int n = w * 64 + 16 * j + l15;
            const size_t idx = (size_t)row * CD + n;
            const float addv = ADDBF ? bf2f(((const short*)addp)[idx])
                                     : ((const float*)addp)[idx];
            const float x = acc[j][rr] + biasv[n] + addv;
            v[rr][j] = x;
            s += x; sq += x * x;
        }
        #pragma unroll
        for (int off = 1; off < 16; off <<= 1) {
            s  += __shfl_xor(s, off);
            sq += __shfl_xor(sq, off);
        }
        if (l15 == 0) {
            redS[quad * 4 + rr][w] = s;
            redQ[quad * 4 + rr][w] = sq;
        }
    }
    __syncthreads();

    #pragma unroll
    for (int rr = 0; rr < 4; ++rr) {
        const int r16 = quad * 4 + rr;
        const int row = m0 + r16;
        const float s  = (redS[r16][0] + redS[r16][1]) + (redS[r16][2] + redS[r16][3]);
        const float sq = (redQ[r16][0] + redQ[r16][1]) + (redQ[r16][2] + redQ[r16][3]);
        const float mean = s * (1.f / CD);
        const float var  = sq * (1.f / CD) - mean * mean;
        const float rstd = rsqrtf(var + CEPS);
        #pragma unroll
        for (int j = 0; j < 4; ++j) {
            const int n = w * 64 + 16 * j + l15;
            const float y = (v[rr][j] - mean) * rstd * gw[n] + be[n];
            if (OUTF) outf[(size_t)row * CD + n] = y;
            if (OUTB) outb[(size_t)row * CD + n] = f2bf(y);
        }
    }
}

// ---------------------------------------------------------------------------
// Prep: src->bf16, weight transposes via 64x64 LDS tiles, biases packed.
// ---------------------------------------------------------------------------
__global__ __launch_bounds__(256)
void prep(const float* __restrict__ src,
          const float* __restrict__ Wq, const float* __restrict__ Wk,
          const float* __restrict__ Wv, const float* __restrict__ Wo,
          const float* __restrict__ W1, const float* __restrict__ W2,
          const float* __restrict__ bq, const float* __restrict__ bk,
          const float* __restrict__ bv, const float* __restrict__ bo,
          const float* __restrict__ b1, const float* __restrict__ b2,
          short* __restrict__ src_bf,
          short* __restrict__ wqkvT, short* __restrict__ woT,
          short* __restrict__ w1T, short* __restrict__ w2T,
          float* __restrict__ bpack)
{
    __shared__ float tile[64][65];
    const int bx = blockIdx.x, t = threadIdx.x;
    if (bx < 2048) {                                   // src cast: 512K float4
        const int i = bx * 256 + t;
        const float4 v = ((const float4*)src)[i];
        short4 o;
        o.x = f2bf(v.x); o.y = f2bf(v.y); o.z = f2bf(v.z); o.w = f2bf(v.w);
        ((short4*)src_bf)[i] = o;
    } else if (bx < 2288) {                            // weight transposes
        const int tt = bx - 2048;
        const float* S; short* D;
        int Sstride, Dstride, k0, srccol, dstrow;
        if (tt < 96) {                                 // wqkv: 24x4 tiles
            const int tk = tt & 3, tn = tt >> 2;
            const int ng = tn * 64;
            Sstride = 256; Dstride = 256; k0 = tk * 64;
            dstrow = tn * 64; D = wqkvT;
            if (ng < 256)      { S = Wq; srccol = ng; }
            else if (ng < 512) { S = Wk; srccol = ng - 256; }
            else { const int r = (ng - 512) >> 8;
                   S = Wv + (size_t)r * 65536; srccol = (ng - 512) & 255; }
        } else if (tt < 112) {                         // wo: 4x4
            const int u = tt - 96, tk = u & 3, tn = u >> 2;
            S = Wo; Sstride = 256; D = woT; Dstride = 256;
            k0 = tk * 64; srccol = tn * 64; dstrow = tn * 64;
        } else if (tt < 176) {                         // w1: 16x4
            const int u = tt - 112, tk = u & 3, tn = u >> 2;
            S = W1; Sstride = 1024; D = w1T; Dstride = 256;
            k0 = tk * 64; srccol = tn * 64; dstrow = tn * 64;
        } else {                                       // w2: 4x16
            const int u = tt - 176, tk = u & 15, tn = u >> 4;
            S = W2; Sstride = 256; D = w2T; Dstride = 1024;
            k0 = tk * 64; srccol = tn * 64; dstrow = tn * 64;
        }
        #pragma unroll
        for (int u2 = 0; u2 < 4; ++u2) {               // coalesced read
            const int kl = (t >> 4) + u2 * 16;
            const int nl = (t & 15) * 4;
            const float4 v = *(const float4*)&S[(size_t)(k0 + kl) * Sstride + srccol + nl];
            tile[kl][nl + 0] = v.x; tile[kl][nl + 1] = v.y;
            tile[kl][nl + 2] = v.z; tile[kl][nl + 3] = v.w;
        }
        __syncthreads();
        #pragma unroll
        for (int u2 = 0; u2 < 4; ++u2) {               // coalesced write
            const int nl = (t >> 4) + u2 * 16;
            const int kl = (t & 15) * 4;
            short4 o;
            o.x = f2bf(tile[kl + 0][nl]); o.y = f2bf(tile[kl + 1][nl]);
            o.z = f2bf(tile[kl + 2][nl]); o.w = f2bf(tile[kl + 3][nl]);
            *(short4*)&D[(size_t)(dstrow + nl) * Dstride + k0 + kl] = o;
        }
    } else {                                           // biases: 3072
        const int idx = (bx - 2288) * 256 + t;
        float bvv;
        if (idx < 256)       bvv = bq[idx];
        else if (idx < 512)  bvv = bk[idx - 256];
        else if (idx < 1536) bvv = bv[idx - 512];
        else if (idx < 1792) bvv = bo[idx - 1536];
        else if (idx < 2816) bvv = b1[idx - 1792];
        else                 bvv = b2[idx - 2816];
        bpack[idx] = bvv;
    }
}

// ---------------------------------------------------------------------------
// Fused relational attention, 2-WAVE blocks (64 Q-rows: 2 waves x 2 chains):
//  - barrier domain = 2 waves only (minimal convergence variance); 1024
//    blocks -> 4 independently-phased blocks/CU fill each other's barriers
//  - each wave still carries TWO dependency chains (hh=0,1) sharing K/V frags
//  - QK^T swapped (sacc = mfma(K,Q)) -> P lane-local; sigma k-order feeds PV
//  - byte-LUT masks via v_perm with adj byte as selector
//  - V^T staged by global_load_lds 2-deep ring; K/adjsel direct from L2
// One __syncthreads per j-tile.  XCD-aware 1D grid (b = g & 7).
// ---------------------------------------------------------------------------
__global__ __launch_bounds__(128, 2)
void attn_mfma(const short* __restrict__ qg, const short* __restrict__ kg,
               const short* __restrict__ vt, const unsigned char* __restrict__ adjsel,
               short* __restrict__ outh)
{
    __shared__ __align__(16) short vtl[2][8192];  // [buf][r*2048 + d*64 + gc*8]

    const int t    = threadIdx.x;     // 0..127
    const int lane = t & 63;
    const int w    = t >> 6;          // wave 0..1
    const int quad = lane >> 4;
    const int l15  = lane & 15;
    const int g    = blockIdx.x;      // 1D grid, XCD-aware decode
    const int b    = g & 7;           // same XCD for whole batch
    const int h    = (g >> 3) & 7;
    const int i0   = (g >> 6) * 64;   // 16 tiles of 64 rows
    const int bhh  = b * CH + h;
    const size_t bh = (size_t)bhh;

    v8s qfrag[2];
    #pragma unroll
    for (int hh = 0; hh < 2; ++hh)
        qfrag[hh] = *(const v8s*)&qg[(bh * CN + i0 + 32 * w + 16 * hh + l15) * CDH + quad * 8];

    // V DMA sources: thread t stages granule gl = t + 128u (u<8); LDS granule
    // (r,d,gc) holds global granule gc^(d&7) of V^T row (r,d) in this j-tile.
    const short* vsrc[8];
    #pragma unroll
    for (int u = 0; u < 8; ++u) {
        const int gl = t + 128 * u;
        const int r = gl >> 8, d = (gl >> 3) & 31, gc = gl & 7;
        vsrc[u] = vt + ((size_t)(r * 64 + bhh) * CDH + d) * CN + (gc ^ (d & 7)) * 8;
    }
    // K direct: A-operand rows l15, k-chunk quad*8
    const short* kbase = kg + (bh * CN + l15) * CDH + quad * 8;
    // adjsel direct: row i0+32w+16hh+l15, int2 (kb, quad) of the 64B slice
    const unsigned char* abase[2];
    #pragma unroll
    for (int hh = 0; hh < 2; ++hh)
        abase[hh] = adjsel + ((size_t)(b * CN) + i0 + 32 * w + 16 * hh + l15) * CN + quad * 8;

    v4f oacc[2][2][2];                 // [hh][cb][kb]
    #pragma unroll
    for (int hh = 0; hh < 2; ++hh)
        #pragma unroll
        for (int cb = 0; cb < 2; ++cb)
            #pragma unroll
            for (int kb = 0; kb < 2; ++kb) oacc[hh][cb][kb] = (v4f){0.f, 0.f, 0.f, 0.f};
    float plsum[2] = {0.f, 0.f};
    const int psw = (l15 & 7) * 8;         // vfrag granule XOR (pre-scaled)

    // ---- prologue: prefetch tile 0 ----
    #pragma unroll
    for (int u = 0; u < 8; ++u)
        async_copy16(vsrc[u], &vtl[0][(t + 128 * u) * 8]);
    v8s kpre[4];
    #pragma unroll
    for (int jb = 0; jb < 4; ++jb)
        kpre[jb] = *(const v8s*)(kbase + (16 * jb) * CDH);
    int2 apre[2][2];
    #pragma unroll
    for (int hh = 0; hh < 2; ++hh) {
        apre[hh][0] = *(const int2*)(abase[hh]);
        apre[hh][1] = *(const int2*)(abase[hh] + 32);
    }

    for (int jt = 0; jt < 16; ++jt) {
        __syncthreads();   // vtl[jt&1] staged; other buf free for prefetch
        const int p = jt & 1;

        // ---- QK swapped, both halves share kpre ----
        v4f sacc[2][4];
        #pragma unroll
        for (int hh = 0; hh < 2; ++hh)
            #pragma unroll
            for (int jb = 0; jb < 4; ++jb)
                sacc[hh][jb] = __builtin_amdgcn_mfma_f32_16x16x32_bf16(
                    kpre[jb], qfrag[hh], (v4f){0.f, 0.f, 0.f, 0.f}, 0, 0, 0);

        // ---- issue prefetches for tile jt+1 (wrap harmless on last iter) ----
        int2 aa[2][2];
        #pragma unroll
        for (int hh = 0; hh < 2; ++hh) {
            aa[hh][0] = apre[hh][0];
            aa[hh][1] = apre[hh][1];
        }
        const int jn = (jt + 1) & 15;
        #pragma unroll
        for (int u = 0; u < 8; ++u)
            async_copy16(vsrc[u] + jn * 64, &vtl[p ^ 1][(t + 128 * u) * 8]);
        #pragma unroll
        for (int jb = 0; jb < 4; ++jb)
            kpre[jb] = *(const v8s*)(kbase + (jn * 64 + 16 * jb) * CDH);
        #pragma unroll
        for (int hh = 0; hh < 2; ++hh) {
            apre[hh][0] = *(const int2*)(abase[hh] + jn * 64);
            apre[hh][1] = *(const int2*)(abase[hh] + jn * 64 + 32);
        }

        // ---- softmax numerators, both halves, all in registers ----
        float pv[2][4][4];   // [hh][jb][rr] = P[i=l15][j=16jb+4quad+rr]
        #pragma unroll
        for (int hh = 0; hh < 2; ++hh) {
            #pragma unroll
            for (int jb = 0; jb < 4; ++jb)
                #pragma unroll
                for (int rr = 0; rr < 4; ++rr) pv[hh][jb][rr] = exp2f(sacc[hh][jb][rr]);
            plsum[hh] += ((pv[hh][0][0] + pv[hh][0][1]) + (pv[hh][0][2] + pv[hh][0][3]))
                       + ((pv[hh][1][0] + pv[hh][1][1]) + (pv[hh][1][2] + pv[hh][1][3]))
                       + ((pv[hh][2][0] + pv[hh][2][1]) + (pv[hh][2][2] + pv[hh][2][3]))
                       + ((pv[hh][3][0] + pv[hh][3][1]) + (pv[hh][3][2] + pv[hh][3][3]));
        }

        // ---- PV: vf loaded once per kb, reused by both halves ----
        #pragma unroll
        for (int kb = 0; kb < 2; ++kb) {
            v8s vf[4][2];
            #pragma unroll
            for (int r = 0; r < 4; ++r)
                #pragma unroll
                for (int cb = 0; cb < 2; ++cb)
                    vf[r][cb] = *(const v8s*)&vtl[p][r * 2048 +
                        (16 * cb + l15) * 64 + (((4 * kb + quad) * 8) ^ psw)];

            #pragma unroll
            for (int hh = 0; hh < 2; ++hh) {
                // A-operand dwords: e = {0..7} = rr of jb=kb then rr of jb=kb+2
                const unsigned P[4] = {
                    cvtpk_bf16(pv[hh][kb][0],     pv[hh][kb][1]),
                    cvtpk_bf16(pv[hh][kb][2],     pv[hh][kb][3]),
                    cvtpk_bf16(pv[hh][kb + 2][0], pv[hh][kb + 2][1]),
                    cvtpk_bf16(pv[hh][kb + 2][2], pv[hh][kb + 2][3])};
                const int2 a2 = aa[hh][kb];
                // D[u] = [v0,v0,v1,v1] bytes for pair u
                const unsigned D[4] = {
                    __builtin_amdgcn_perm((unsigned)a2.x, (unsigned)a2.x, 0x01010000u),
                    __builtin_amdgcn_perm((unsigned)a2.x, (unsigned)a2.x, 0x03030202u),
                    __builtin_amdgcn_perm((unsigned)a2.y, (unsigned)a2.y, 0x01010000u),
                    __builtin_amdgcn_perm((unsigned)a2.y, (unsigned)a2.y, 0x03030202u)};
                unsigned pfm[4][4];
                #pragma unroll
                for (int r = 0; r < 4; ++r) {
                    const unsigned tb = 0xffu << (8 * r);   // one-hot byte table
                    #pragma unroll
                    for (int u = 0; u < 4; ++u)
                        pfm[r][u] = P[u] & __builtin_amdgcn_perm(0u, tb, D[u]);
                }
                __builtin_amdgcn_s_setprio(1);
                #pragma unroll
                for (int r = 0; r < 4; ++r) {
                    const v8s pfr = __builtin_bit_cast(v8s,
                        make_uint4(pfm[r][0], pfm[r][1], pfm[r][2], pfm[r][3]));
                    #pragma unroll
                    for (int cb = 0; cb < 2; ++cb)
                        oacc[hh][cb][kb] = __builtin_amdgcn_mfma_f32_16x16x32_bf16(
                            pfr, vf[r][cb], oacc[hh][cb][kb], 0, 0, 0);
                }
                __builtin_amdgcn_s_setprio(0);
            }
        }
    }

    // ---- epilogue: merge split accumulators, reduce plsum, normalize ----
    #pragma unroll
    for (int hh = 0; hh < 2; ++hh) {
        v4f ofin[2];
        ofin[0] = oacc[hh][0][0] + oacc[hh][0][1];
        ofin[1] = oacc[hh][1][0] + oacc[hh][1][1];
        float plF = plsum[hh];
        plF += __shfl_xor(plF, 16);
        plF += __shfl_xor(plF, 32);        // lane x: denom for row i=x&15
        #pragma unroll
        for (int rr = 0; rr < 4; ++rr) {
            const float inv = 1.f / __shfl(plF, quad * 4 + rr);
            const int row = i0 + 32 * w + 16 * hh + quad * 4 + rr;
            #pragma unroll
            for (int cb = 0; cb < 2; ++cb)
                outh[((size_t)b * CN + row) * CD + h * CDH + 16 * cb + l15] =
                    f2bf(ofin[cb][rr] * inv);
        }
    }
}

// ---------------------------------------------------------------------------
extern "C" void kernel_launch(void* const* d_in, const int* in_sizes, int n_in,
                              void* d_out, int out_size, void* d_ws, size_t ws_size,
                              hipStream_t stream)
{
    const float* src = (const float*)d_in[0];
    const int*   adj = (const int*)d_in[1];
    const float* Wq  = (const float*)d_in[2];
    const float* bq  = (const float*)d_in[3];
    const float* Wk  = (const float*)d_in[4];
    const float* bk  = (const float*)d_in[5];
    const float* Wv  = (const float*)d_in[6];
    const float* bv  = (const float*)d_in[7];
    const float* Wo  = (const float*)d_in[8];
    const float* bo  = (const float*)d_in[9];
    const float* W1  = (const float*)d_in[10];
    const float* b1  = (const float*)d_in[11];
    const float* W2  = (const float*)d_in[12];
    const float* b2  = (const float*)d_in[13];
    const float* g1  = (const float*)d_in[14];
    const float* be1 = (const float*)d_in[15];
    const float* g2  = (const float*)d_in[16];
    const float* be2 = (const float*)d_in[17];
    float* out = (float*)d_out;

    char* wsb = (char*)d_ws;
    const size_t MB = (size_t)1 << 20;

    // workspace layout (42 MB with aliasing)
    unsigned char* adjsel = (unsigned char*)(wsb);          // [0,8) MB byte-pair adj
    short* qkv_bf = (short*)(wsb + 8 * MB);                 // [8,32): q,k planes + vT
    short* src_bf = (short*)(wsb + 32 * MB);                // [32,36)
    short* wqkvT  = (short*)(wsb + 36 * MB);                // 768 KB
    short* woT    = (short*)(wsb + 36 * MB + 768 * 1024);   // 128 KB
    short* w1T    = (short*)(wsb + 36 * MB + 896 * 1024);   // 512 KB
    short* w2T    = (short*)(wsb + 36 * MB + 1408 * 1024);  // 512 KB
    float* bpack  = (float*)(wsb + 36 * MB + 1920 * 1024);  // 12 KB
    short* heads_bf = (short*)(wsb + 38 * MB);              // [38,42)
    short* x_bf   = (short*)(wsb + 32 * MB);                // reuse src_bf (LN1 out)
    short* h1_bf  = (short*)(wsb + 16 * MB);                // reuse vT (dead post-attn)

    const int M = CB * CN;        // 8192
    dim3 blk(256);

    // prep: src cast, coalesced weight transposes, biases (2300 blocks)
    prep<<<dim3(2300), blk, 0, stream>>>(src, Wq, Wk, Wv, Wo, W1, W2,
        bq, bk, bv, bo, b1, b2, src_bf, wqkvT, woT, w1T, w2T, bpack);

    // fused QK + V^T projection (128x128 tiles) + sigma byte pack: 1280 blocks
    proj_kernel<<<dim3(1280), blk, 32768, stream>>>(
        src_bf, wqkvT, bpack, qkv_bf, adj, adjsel);

    // fused relational MFMA attention (2-wave blocks, XCD-aware 1D grid)
    attn_mfma<<<dim3(1024), dim3(128), 0, stream>>>(
        qkv_bf, qkv_bf + SZH, qkv_bf + 2 * SZH, adjsel, heads_bf);

    // O-projection + bias + residual(src fp32) + LN1 -> x_bf bf16 only
    gemm_ln32<false, true, false><<<dim3(M / 16), blk, 0, stream>>>(
        heads_bf, woT, bpack + 1536, src, g1, be1, nullptr, x_bf, CD);

    // FFN1 (128x128 tiles): 512 blocks
    gemm_mfma<128, 128, MODE_FFN1><<<dim3(M / 128, CFF / 128), blk, 32768, stream>>>(
        x_bf, w1T, bpack + 1792, h1_bf, M, CD, CFF);

    // FFN2 + bias + residual(x_bf bf16) + LN2 -> out fp32
    gemm_ln32<true, false, true><<<dim3(M / 16), blk, 0, stream>>>(
        h1_bf, w2T, bpack + 2816, x_bf, g2, be2, out, nullptr, CFF);
}

// Round 10
// 215.870 us; speedup vs baseline: 1.0053x; 1.0053x over previous
//
#include <hip/hip_runtime.h>
#include <hip/hip_bf16.h>
#include <cmath>

// Problem constants (fixed by the reference)
constexpr int CB  = 8;     // batch
constexpr int CN  = 1024;  // sequence length
constexpr int CD  = 256;   // model dim
constexpr int CH  = 8;     // heads
constexpr int CDH = 32;    // head dim
constexpr int CR  = 4;     // relation types (adj value 4 = none)
constexpr int CFF = 1024;  // ffn dim
constexpr float CEPS = 1e-5f;
constexpr float CS = 0.25503480f;   // (1/sqrt(32)) * log2(e), folded into Q
constexpr size_t SZH = (size_t)CB * CH * CN * CDH;  // 2M: one head-plane

#define MODE_QK    0   // scatter bf16 q/k head-major planes, +bias (cols 0..511)
#define MODE_FFN1  2   // +bias, tanh-gelu -> bf16
#define MODE_VT    4   // V^T gemm (A=weight rows, B=src rows): sigma column store

typedef float v4f __attribute__((ext_vector_type(4)));
typedef short v8s __attribute__((ext_vector_type(8)));

static __device__ __forceinline__ short f2bf(float f) {
    unsigned u = __builtin_bit_cast(unsigned, f);
    u += 0x7fff + ((u >> 16) & 1);          // round-to-nearest-even
    return (short)(u >> 16);
}
static __device__ __forceinline__ float bf2f(short s) {
    unsigned u = ((unsigned)(unsigned short)s) << 16;
    return __builtin_bit_cast(float, u);
}
static __device__ __forceinline__ unsigned cvtpk_bf16(float lo, float hi) {
    unsigned r;
    asm("v_cvt_pk_bf16_f32 %0, %1, %2" : "=v"(r) : "v"(lo), "v"(hi));
    return r;
}

static __device__ __forceinline__ void async_copy16(const void* g, void* l) {
    __builtin_amdgcn_global_load_lds(
        (const __attribute__((address_space(1))) void*)g,
        (__attribute__((address_space(3))) void*)l, 16, 0, 0);
}

// PV k-order permutation sigma(j): c[5]=j[4], c[4:3]=j[3:2], c[2]=j[5],
// c[1:0]=j[1:0].  With swapped QK^T (sacc = mfma(K,Q)), lane (quad,l15)
// holds P[i=l15][j=16jb+4quad+rr], and sigma maps those 16 j's exactly onto
// PV A-operand k-slots {kb*32 + quad*8 + e} -> P never touches LDS.
// adjsel stores adj as BYTES in sigma pair order; at PV time the byte value
// itself is a v_perm selector into a one-hot 0xff table (v=4 -> zero operand).

// ---------------------------------------------------------------------------
// bf16 MFMA GEMM body (device fn, dynamic LDS): epilogue(A[M,K] @ Bw[N,K])
// BM x BN tile, 4 waves 2x2, BK=32 double-buffered 1-deep prefetch.
// ---------------------------------------------------------------------------
template<int BM, int BN, int MODE>
__device__ __forceinline__ void gemm_body(
    const short* __restrict__ A, const short* __restrict__ Bw,
    const float* __restrict__ biasv, void* __restrict__ dest,
    int M, int K, int Nw, int bx, int by, short* smem)
{
    constexpr int WTM = BM / 2, WTN = BN / 2;
    constexpr int TM = WTM / 16, TN = WTN / 16;
    short* As = smem;                    // [2][BM*32]
    short* Bs = smem + 2 * BM * 32;      // [2][BN*32]

    const int t    = threadIdx.x;
    const int lane = t & 63;
    const int w    = t >> 6;
    const int quad = lane >> 4, l15 = lane & 15;
    const int wm = w >> 1, wn = w & 1;
    const int m0 = bx * BM, n0 = by * BN;

    const int srow = lane >> 2;
    const int scol = (lane & 3) * 8;

    v4f acc[TM][TN];
    #pragma unroll
    for (int i = 0; i < TM; ++i)
        #pragma unroll
        for (int j = 0; j < TN; ++j) acc[i][j] = (v4f){0.f, 0.f, 0.f, 0.f};

    const int NK = K >> 5;

    auto stage = [&](int buf, int kt) {
        #pragma unroll
        for (int u = 0; u < BM / 64; ++u) {
            const int e0 = (w * (BM / 64) + u) * 512;
            const int row = (e0 >> 5) + srow;
            async_copy16(A + (size_t)(m0 + row) * K + kt + scol,
                         &As[buf * BM * 32 + e0]);
        }
        #pragma unroll
        for (int u = 0; u < BN / 64; ++u) {
            const int e0 = (w * (BN / 64) + u) * 512;
            const int row = (e0 >> 5) + srow;
            async_copy16(Bw + (size_t)(n0 + row) * K + kt + scol,
                         &Bs[buf * BN * 32 + e0]);
        }
    };

    stage(0, 0);

    for (int it = 0; it < NK; ++it) {
        __syncthreads();
        if (it + 1 < NK) stage((it + 1) & 1, (it + 1) << 5);

        const int buf = it & 1;
        v8s af[TM], bfr[TN];
        #pragma unroll
        for (int i = 0; i < TM; ++i)
            af[i] = *(const v8s*)&As[buf * BM * 32 +
                                     (wm * WTM + i * 16 + l15) * 32 + quad * 8];
        #pragma unroll
        for (int j = 0; j < TN; ++j)
            bfr[j] = *(const v8s*)&Bs[buf * BN * 32 +
                                      (wn * WTN + j * 16 + l15) * 32 + quad * 8];
        #pragma unroll
        for (int i = 0; i < TM; ++i)
            #pragma unroll
            for (int j = 0; j < TN; ++j)
                acc[i][j] = __builtin_amdgcn_mfma_f32_16x16x32_bf16(
                    af[i], bfr[j], acc[i][j], 0, 0, 0);
    }

    #pragma unroll
    for (int i = 0; i < TM; ++i) {
        #pragma unroll
        for (int j = 0; j < TN; ++j) {
            const int mb = m0 + wm * WTM + i * 16 + quad * 4;   // row of rr=0
            const int n  = n0 + wn * WTN + j * 16 + l15;
            float vals[4];
            if (MODE == MODE_VT) {
                #pragma unroll
                for (int rr = 0; rr < 4; ++rr) vals[rr] = acc[i][j][rr] + biasv[mb + rr];
            } else {
                #pragma unroll
                for (int rr = 0; rr < 4; ++rr) vals[rr] = acc[i][j][rr] + biasv[n];
            }

            if (MODE == MODE_QK) {
                // fold softmax scale into Q (q-plane blocks have n0 < 256)
                if (n0 < 256) {
                    #pragma unroll
                    for (int rr = 0; rr < 4; ++rr) vals[rr] *= CS;
                }
                const int b = mb >> 10, ii0 = mb & 1023;
                const int plane = n >> 8, nn = n & 255;
                const int h = nn >> 5, d = nn & 31;
                #pragma unroll
                for (int rr = 0; rr < 4; ++rr)
                    ((short*)dest)[(size_t)plane * SZH +
                        (((size_t)(b * CH + h)) * CN + ii0 + rr) * CDH + d] =
                        f2bf(vals[rr]);
            } else if (MODE == MODE_VT) {
                // sigma column permutation within each 64-token tile (see top)
                const int b = n >> 10, ii = n & 1023;
                const int jj = ii & 63;
                const int cc = (((jj >> 4) & 1) << 5) | (((jj >> 2) & 3) << 3) |
                               (((jj >> 5) & 1) << 2) | (jj & 3);
                const int iip = (ii & ~63) | cc;
                #pragma unroll
                for (int rr = 0; rr < 4; ++rr) {
                    const int m = mb + rr;
                    const int r2 = m >> 8, hd = m & 255;
                    const int h = hd >> 5, d = hd & 31;
                    ((short*)dest)[2 * SZH +
                        (((size_t)(r2 * 64 + b * CH + h)) * CDH + d) * CN + iip] =
                        f2bf(vals[rr]);
                }
            } else { // MODE_FFN1: tanh-gelu -> bf16 (x*E/(E+1))
                #pragma unroll
                for (int rr = 0; rr < 4; ++rr) {
                    const size_t idx = (size_t)(mb + rr) * Nw + n;
                    const float xx = vals[rr];
                    const float E = exp2f(2.302217f * (xx + 0.044715f * xx * xx * xx));
                    ((short*)dest)[idx] = f2bf(xx * E / (E + 1.f));
                }
            }
        }
    }
}

template<int BM, int BN, int MODE>
__global__ __launch_bounds__(256)
void gemm_mfma(const short* __restrict__ A, const short* __restrict__ Bw,
               const float* __restrict__ biasv, void* __restrict__ dest,
               int M, int K, int Nw)
{
    extern __shared__ short smem[];
    gemm_body<BM, BN, MODE>(A, Bw, biasv, dest, M, K, Nw,
                            blockIdx.x, blockIdx.y, smem);
}

// ---------------------------------------------------------------------------
// Fused projection dispatch (128x128 m97-style tiles):
//   blocks 0..255   = QK  (8192x512, K=256)
//   blocks 256..767 = V^T (1024x8192, K=256)
//   blocks 768..1279= adj int32 -> BYTE-pair pack in sigma order (adjsel)
// ---------------------------------------------------------------------------
__global__ __launch_bounds__(256)
void proj_kernel(const short* __restrict__ src_bf, const short* __restrict__ wqkvT,
                 const float* __restrict__ bpack, short* __restrict__ qkv,
                 const int* __restrict__ adj, unsigned char* __restrict__ adjsel)
{
    extern __shared__ short smem[];
    const int g = blockIdx.x;
    if (g < 256) {
        gemm_body<128, 128, MODE_QK>(src_bf, wqkvT, bpack, qkv,
                                     8192, 256, 512, g >> 2, g & 3, smem);
    } else if (g < 768) {
        const int h2 = g - 256;
        gemm_body<128, 128, MODE_VT>(wqkvT + 512 * 256, src_bf, bpack + 512,
                                     qkv, 1024, 256, 8192, h2 & 7, h2 >> 3, smem);
    } else {
        // sigma-order byte pack: int2 (row, dwi) holds adj bytes for the 8 j's
        // j0+{0..3}, j0+32+{0..3} with j0 = T*64 + (kq&3)*4 + (kq>>2)*16,
        // T = dwi>>3, kq = dwi&7  (kq = kb*4 + quad).
        const int nout = CB * CN * CN / 8;           // 1M int2 (8 j's each)
        for (int i = (g - 768) * 256 + threadIdx.x; i < nout; i += 512 * 256) {
            const int dwi = i & 127;
            const int row = i >> 7;
            const int T   = dwi >> 3, kq = dwi & 7;
            const int j0  = T * 64 + (kq & 3) * 4 + (kq >> 2) * 16;
            const int* p = adj + (size_t)row * CN + j0;
            const int4 q0 = *(const int4*)(p);
            const int4 q1 = *(const int4*)(p + 32);
            int2 o;
            o.x = (q0.x & 0xff) | ((q0.y & 0xff) << 8) |
                  ((q0.z & 0xff) << 16) | ((q0.w & 0xff) << 24);
            o.y = (q1.x & 0xff) | ((q1.y & 0xff) << 8) |
                  ((q1.z & 0xff) << 16) | ((q1.w & 0xff) << 24);
            ((int2*)adjsel)[i] = o;
        }
    }
}

// ---------------------------------------------------------------------------
// FUSED GEMM + bias + residual + LayerNorm, BM=32 (2x2 waves), BK=64:
// 16 MFMA/wave between barriers (2x the BM=16 version), B re-staging traffic
// halved (256 blocks instead of 512).  Wave (wr,wc): rows wr*16+quad*4+rr,
// cols wc*128+16j+l15 (j=0..7).  Granule-XOR swizzle (source-side) on the
// 128B-stride LDS rows -> conflict-light ds_read_b128.
// OUTF: write fp32 result; OUTB: write bf16 result; ADDBF: residual is bf16.
// ---------------------------------------------------------------------------
template<bool OUTF, bool OUTB, bool ADDBF>
__global__ __launch_bounds__(256)
void gemm_ln32(const short* __restrict__ A, const short* __restrict__ Bw,
               const float* __restrict__ biasv, const void* __restrict__ addp,
               const float* __restrict__ gw, const float* __restrict__ be,
               float* __restrict__ outf, short* __restrict__ outb, int K)
{
    __shared__ short As[2][32 * 64];    // 8 KB
    __shared__ short Bs[2][256 * 64];   // 64 KB
    __shared__ float redS[32][2], redQ[32][2];

    const int t    = threadIdx.x;
    const int lane = t & 63;
    const int w    = t >> 6;
    const int wr   = w >> 1;          // row half (16 rows)
    const int wc   = w & 1;           // col half (128 cols)
    const int quad = lane >> 4, l15 = lane & 15;
    const int m0   = blockIdx.x * 32;
    const int xsw  = l15 & 7;         // read-side granule XOR

    v4f acc[8];
    #pragma unroll
    for (int j = 0; j < 8; ++j) acc[j] = (v4f){0.f, 0.f, 0.f, 0.f};

    const int NK = K >> 6;

    auto stage = [&](int buf, int kt) {
        {   // A: 32 rows x 64 cols = 256 granules -> 1/thread
            const int row = t >> 3, gc = t & 7;
            async_copy16(A + (size_t)(m0 + row) * K + kt + ((gc ^ (row & 7)) * 8),
                         &As[buf][t * 8]);
        }
        #pragma unroll
        for (int u = 0; u < 8; ++u) {   // B: 256 rows x 64 cols = 2048 granules
            const int gl = t + 256 * u;
            const int row = gl >> 3, gc = gl & 7;
            async_copy16(Bw + (size_t)row * K + kt + ((gc ^ (row & 7)) * 8),
                         &Bs[buf][gl * 8]);
        }
    };

    stage(0, 0);

    for (int it = 0; it < NK; ++it) {
        __syncthreads();
        if (it + 1 < NK) stage((it + 1) & 1, (it + 1) << 6);

        const int buf = it & 1;
        #pragma unroll
        for (int half = 0; half < 2; ++half) {
            const int gr = (quad + 4 * half) ^ xsw;
            const v8s af = *(const v8s*)&As[buf][(wr * 16 + l15) * 64 + gr * 8];
            #pragma unroll
            for (int j = 0; j < 8; ++j) {
                const v8s bfr = *(const v8s*)&Bs[buf][(wc * 128 + 16 * j + l15) * 64 + gr * 8];
                acc[j] = __builtin_amdgcn_mfma_f32_16x16x32_bf16(af, bfr, acc[j], 0, 0, 0);
            }
        }
    }

    float v[4][8];
    #pragma unroll
    for (int rr = 0; rr < 4; ++rr) {
        const int row = m0 + wr * 16 + quad * 4 + rr;
        float s = 0.f, sq = 0.f;
        #pragma unroll
        for (int j = 0; j < 8; ++j) {
            const int n = wc * 128 + 16 * j + l15;
            const size_t idx = (size_t)row * CD + n;
            const float addv = ADDBF ? bf2f(((const short*)addp)[idx])
                                     : ((const float*)addp)[idx];
            const float x = acc[j][rr] + biasv[n] + addv;
            v[rr][j] = x;
            s += x; sq += x * x;
        }
        #pragma unroll
        for (int off = 1; off < 16; off <<= 1) {
            s  += __shfl_xor(s, off);
            sq += __shfl_xor(sq, off);
        }
        if (l15 == 0) {
            redS[wr * 16 + quad * 4 + rr][wc] = s;
            redQ[wr * 16 + quad * 4 + rr][wc] = sq;
        }
    }
    __syncthreads();

    #pragma unroll
    for (int rr = 0; rr < 4; ++rr) {
        const int r32 = wr * 16 + quad * 4 + rr;
        const int row = m0 + r32;
        const float s  = redS[r32][0] + redS[r32][1];
        const float sq = redQ[r32][0] + redQ[r32][1];
        const float mean = s * (1.f / CD);
        const float var  = sq * (1.f / CD) - mean * mean;
        const float rstd = rsqrtf(var + CEPS);
        #pragma unroll
        for (int j = 0; j < 8; ++j) {
            const int n = wc * 128 + 16 * j + l15;
            const float y = (v[rr][j] - mean) * rstd * gw[n] + be[n];
            if (OUTF) outf[(size_t)row * CD + n] = y;
            if (OUTB) outb[(size_t)row * CD + n] = f2bf(y);
        }
    }
}

// ---------------------------------------------------------------------------
// Prep: src->bf16, weight transposes via 64x64 LDS tiles, biases packed.
// ---------------------------------------------------------------------------
__global__ __launch_bounds__(256)
void prep(const float* __restrict__ src,
          const float* __restrict__ Wq, const float* __restrict__ Wk,
          const float* __restrict__ Wv, const float* __restrict__ Wo,
          const float* __restrict__ W1, const float* __restrict__ W2,
          const float* __restrict__ bq, const float* __restrict__ bk,
          const float* __restrict__ bv, const float* __restrict__ bo,
          const float* __restrict__ b1, const float* __restrict__ b2,
          short* __restrict__ src_bf,
          short* __restrict__ wqkvT, short* __restrict__ woT,
          short* __restrict__ w1T, short* __restrict__ w2T,
          float* __restrict__ bpack)
{
    __shared__ float tile[64][65];
    const int bx = blockIdx.x, t = threadIdx.x;
    if (bx < 2048) {                                   // src cast: 512K float4
        const int i = bx * 256 + t;
        const float4 v = ((const float4*)src)[i];
        short4 o;
        o.x = f2bf(v.x); o.y = f2bf(v.y); o.z = f2bf(v.z); o.w = f2bf(v.w);
        ((short4*)src_bf)[i] = o;
    } else if (bx < 2288) {                            // weight transposes
        const int tt = bx - 2048;
        const float* S; short* D;
        int Sstride, Dstride, k0, srccol, dstrow;
        if (tt < 96) {                                 // wqkv: 24x4 tiles
            const int tk = tt & 3, tn = tt >> 2;
            const int ng = tn * 64;
            Sstride = 256; Dstride = 256; k0 = tk * 64;
            dstrow = tn * 64; D = wqkvT;
            if (ng < 256)      { S = Wq; srccol = ng; }
            else if (ng < 512) { S = Wk; srccol = ng - 256; }
            else { const int r = (ng - 512) >> 8;
                   S = Wv + (size_t)r * 65536; srccol = (ng - 512) & 255; }
        } else if (tt < 112) {                         // wo: 4x4
            const int u = tt - 96, tk = u & 3, tn = u >> 2;
            S = Wo; Sstride = 256; D = woT; Dstride = 256;
            k0 = tk * 64; srccol = tn * 64; dstrow = tn * 64;
        } else if (tt < 176) {                         // w1: 16x4
            const int u = tt - 112, tk = u & 3, tn = u >> 2;
            S = W1; Sstride = 1024; D = w1T; Dstride = 256;
            k0 = tk * 64; srccol = tn * 64; dstrow = tn * 64;
        } else {                                       // w2: 4x16
            const int u = tt - 176, tk = u & 15, tn = u >> 4;
            S = W2; Sstride = 256; D = w2T; Dstride = 1024;
            k0 = tk * 64; srccol = tn * 64; dstrow = tn * 64;
        }
        #pragma unroll
        for (int u2 = 0; u2 < 4; ++u2) {               // coalesced read
            const int kl = (t >> 4) + u2 * 16;
            const int nl = (t & 15) * 4;
            const float4 v = *(const float4*)&S[(size_t)(k0 + kl) * Sstride + srccol + nl];
            tile[kl][nl + 0] = v.x; tile[kl][nl + 1] = v.y;
            tile[kl][nl + 2] = v.z; tile[kl][nl + 3] = v.w;
        }
        __syncthreads();
        #pragma unroll
        for (int u2 = 0; u2 < 4; ++u2) {               // coalesced write
            const int nl = (t >> 4) + u2 * 16;
            const int kl = (t & 15) * 4;
            short4 o;
            o.x = f2bf(tile[kl + 0][nl]); o.y = f2bf(tile[kl + 1][nl]);
            o.z = f2bf(tile[kl + 2][nl]); o.w = f2bf(tile[kl + 3][nl]);
            *(short4*)&D[(size_t)(dstrow + nl) * Dstride + k0 + kl] = o;
        }
    } else {                                           // biases: 3072
        const int idx = (bx - 2288) * 256 + t;
        float bvv;
        if (idx < 256)       bvv = bq[idx];
        else if (idx < 512)  bvv = bk[idx - 256];
        else if (idx < 1536) bvv = bv[idx - 512];
        else if (idx < 1792) bvv = bo[idx - 1536];
        else if (idx < 2816) bvv = b1[idx - 1792];
        else                 bvv = b2[idx - 2816];
        bpack[idx] = bvv;
    }
}

// ---------------------------------------------------------------------------
// Fused relational attention, 128 Q-rows per block (2 independent halves):
//  - each wave carries TWO dependency chains (hh=0,1) that interleave and
//    self-hide latency; K frags and V frags loaded ONCE, reused by both
//  - QK^T swapped (sacc = mfma(K,Q)) -> P lane-local; sigma k-order feeds PV
//  - byte-LUT masks via v_perm with adj byte as selector
//  - V^T staged by global_load_lds 2-deep ring; K/adjsel direct from L2
// One __syncthreads per j-tile.  XCD-aware 1D grid, 512 blocks (b = g & 7).
// ---------------------------------------------------------------------------
__global__ __launch_bounds__(256, 2)
void attn_mfma(const short* __restrict__ qg, const short* __restrict__ kg,
               const short* __restrict__ vt, const unsigned char* __restrict__ adjsel,
               short* __restrict__ outh)
{
    __shared__ __align__(16) short vtl[2][8192];  // [buf][r*2048 + d*64 + gc*8]

    const int t    = threadIdx.x;
    const int lane = t & 63;
    const int w    = t >> 6;          // wave 0..3
    const int quad = lane >> 4;
    const int l15  = lane & 15;
    const int g    = blockIdx.x;      // 1D grid, XCD-aware decode
    const int b    = g & 7;           // same XCD for whole batch
    const int h    = (g >> 3) & 7;
    const int i0   = (g >> 6) * 128;  // 8 tiles of 128 rows
    const int bhh  = b * CH + h;
    const size_t bh = (size_t)bhh;

    v8s qfrag[2];
    #pragma unroll
    for (int hh = 0; hh < 2; ++hh)
        qfrag[hh] = *(const v8s*)&qg[(bh * CN + i0 + 64 * hh + 16 * w + l15) * CDH + quad * 8];

    // V DMA sources: thread t stages granule gl = t + 256u; LDS granule
    // (r,d,gc) holds global granule gc^(d&7) of V^T row (r,d) in this j-tile.
    const short* vsrc[4];
    #pragma unroll
    for (int u = 0; u < 4; ++u) {
        const int gl = t + 256 * u;
        const int r = gl >> 8, d = (gl >> 3) & 31, gc = gl & 7;
        vsrc[u] = vt + ((size_t)(r * 64 + bhh) * CDH + d) * CN + (gc ^ (d & 7)) * 8;
    }
    // K direct: A-operand rows l15, k-chunk quad*8
    const short* kbase = kg + (bh * CN + l15) * CDH + quad * 8;
    // adjsel direct: row i0+64*hh+16w+l15, int2 (kb, quad) of the 64B slice
    const unsigned char* abase[2];
    #pragma unroll
    for (int hh = 0; hh < 2; ++hh)
        abase[hh] = adjsel + ((size_t)(b * CN) + i0 + 64 * hh + 16 * w + l15) * CN + quad * 8;

    v4f oacc[2][2][2];                 // [hh][cb][kb]
    #pragma unroll
    for (int hh = 0; hh < 2; ++hh)
        #pragma unroll
        for (int cb = 0; cb < 2; ++cb)
            #pragma unroll
            for (int kb = 0; kb < 2; ++kb) oacc[hh][cb][kb] = (v4f){0.f, 0.f, 0.f, 0.f};
    float plsum[2] = {0.f, 0.f};
    const int psw = (l15 & 7) * 8;         // vfrag granule XOR (pre-scaled)

    // ---- prologue: prefetch tile 0 ----
    #pragma unroll
    for (int u = 0; u < 4; ++u)
        async_copy16(vsrc[u], &vtl[0][(t + 256 * u) * 8]);
    v8s kpre[4];
    #pragma unroll
    for (int jb = 0; jb < 4; ++jb)
        kpre[jb] = *(const v8s*)(kbase + (16 * jb) * CDH);
    int2 apre[2][2];
    #pragma unroll
    for (int hh = 0; hh < 2; ++hh) {
        apre[hh][0] = *(const int2*)(abase[hh]);
        apre[hh][1] = *(const int2*)(abase[hh] + 32);
    }

    for (int jt = 0; jt < 16; ++jt) {
        __syncthreads();   // vtl[jt&1] staged; other buf free for prefetch
        const int p = jt & 1;

        // ---- QK swapped, both halves share kpre ----
        v4f sacc[2][4];
        #pragma unroll
        for (int hh = 0; hh < 2; ++hh)
            #pragma unroll
            for (int jb = 0; jb < 4; ++jb)
                sacc[hh][jb] = __builtin_amdgcn_mfma_f32_16x16x32_bf16(
                    kpre[jb], qfrag[hh], (v4f){0.f, 0.f, 0.f, 0.f}, 0, 0, 0);

        // ---- issue prefetches for tile jt+1 (wrap harmless on last iter) ----
        int2 aa[2][2];
        #pragma unroll
        for (int hh = 0; hh < 2; ++hh) {
            aa[hh][0] = apre[hh][0];
            aa[hh][1] = apre[hh][1];
        }
        const int jn = (jt + 1) & 15;
        #pragma unroll
        for (int u = 0; u < 4; ++u)
            async_copy16(vsrc[u] + jn * 64, &vtl[p ^ 1][(t + 256 * u) * 8]);
        #pragma unroll
        for (int jb = 0; jb < 4; ++jb)
            kpre[jb] = *(const v8s*)(kbase + (jn * 64 + 16 * jb) * CDH);
        #pragma unroll
        for (int hh = 0; hh < 2; ++hh) {
            apre[hh][0] = *(const int2*)(abase[hh] + jn * 64);
            apre[hh][1] = *(const int2*)(abase[hh] + jn * 64 + 32);
        }

        // ---- softmax numerators, both halves, all in registers ----
        float pv[2][4][4];   // [hh][jb][rr] = P[i=l15][j=16jb+4quad+rr]
        #pragma unroll
        for (int hh = 0; hh < 2; ++hh) {
            #pragma unroll
            for (int jb = 0; jb < 4; ++jb)
                #pragma unroll
                for (int rr = 0; rr < 4; ++rr) pv[hh][jb][rr] = exp2f(sacc[hh][jb][rr]);
            plsum[hh] += ((pv[hh][0][0] + pv[hh][0][1]) + (pv[hh][0][2] + pv[hh][0][3]))
                       + ((pv[hh][1][0] + pv[hh][1][1]) + (pv[hh][1][2] + pv[hh][1][3]))
                       + ((pv[hh][2][0] + pv[hh][2][1]) + (pv[hh][2][2] + pv[hh][2][3]))
                       + ((pv[hh][3][0] + pv[hh][3][1]) + (pv[hh][3][2] + pv[hh][3][3]));
        }

        // ---- PV: vf loaded once per kb, reused by both halves ----
        #pragma unroll
        for (int kb = 0; kb < 2; ++kb) {
            v8s vf[4][2];
            #pragma unroll
            for (int r = 0; r < 4; ++r)
                #pragma unroll
                for (int cb = 0; cb < 2; ++cb)
                    vf[r][cb] = *(const v8s*)&vtl[p][r * 2048 +
                        (16 * cb + l15) * 64 + (((4 * kb + quad) * 8) ^ psw)];

            #pragma unroll
            for (int hh = 0; hh < 2; ++hh) {
                // A-operand dwords: e = {0..7} = rr of jb=kb then rr of jb=kb+2
                const unsigned P[4] = {
                    cvtpk_bf16(pv[hh][kb][0],     pv[hh][kb][1]),
                    cvtpk_bf16(pv[hh][kb][2],     pv[hh][kb][3]),
                    cvtpk_bf16(pv[hh][kb + 2][0], pv[hh][kb + 2][1]),
                    cvtpk_bf16(pv[hh][kb + 2][2], pv[hh][kb + 2][3])};
                const int2 a2 = aa[hh][kb];
                // D[u] = [v0,v0,v1,v1] bytes for pair u
                const unsigned D[4] = {
                    __builtin_amdgcn_perm((unsigned)a2.x, (unsigned)a2.x, 0x01010000u),
                    __builtin_amdgcn_perm((unsigned)a2.x, (unsigned)a2.x, 0x03030202u),
                    __builtin_amdgcn_perm((unsigned)a2.y, (unsigned)a2.y, 0x01010000u),
                    __builtin_amdgcn_perm((unsigned)a2.y, (unsigned)a2.y, 0x03030202u)};
                unsigned pfm[4][4];
                #pragma unroll
                for (int r = 0; r < 4; ++r) {
                    const unsigned tb = 0xffu << (8 * r);   // one-hot byte table
                    #pragma unroll
                    for (int u = 0; u < 4; ++u)
                        pfm[r][u] = P[u] & __builtin_amdgcn_perm(0u, tb, D[u]);
                }
                __builtin_amdgcn_s_setprio(1);
                #pragma unroll
                for (int r = 0; r < 4; ++r) {
                    const v8s pfr = __builtin_bit_cast(v8s,
                        make_uint4(pfm[r][0], pfm[r][1], pfm[r][2], pfm[r][3]));
                    #pragma unroll
                    for (int cb = 0; cb < 2; ++cb)
                        oacc[hh][cb][kb] = __builtin_amdgcn_mfma_f32_16x16x32_bf16(
                            pfr, vf[r][cb], oacc[hh][cb][kb], 0, 0, 0);
                }
                __builtin_amdgcn_s_setprio(0);
            }
        }
    }

    // ---- epilogue: merge split accumulators, reduce plsum, normalize ----
    #pragma unroll
    for (int hh = 0; hh < 2; ++hh) {
        v4f ofin[2];
        ofin[0] = oacc[hh][0][0] + oacc[hh][0][1];
        ofin[1] = oacc[hh][1][0] + oacc[hh][1][1];
        float plF = plsum[hh];
        plF += __shfl_xor(plF, 16);
        plF += __shfl_xor(plF, 32);        // lane x: denom for row i=x&15
        #pragma unroll
        for (int rr = 0; rr < 4; ++rr) {
            const float inv = 1.f / __shfl(plF, quad * 4 + rr);
            const int row = i0 + 64 * hh + 16 * w + quad * 4 + rr;
            #pragma unroll
            for (int cb = 0; cb < 2; ++cb)
                outh[((size_t)b * CN + row) * CD + h * CDH + 16 * cb + l15] =
                    f2bf(ofin[cb][rr] * inv);
        }
    }
}

// ---------------------------------------------------------------------------
extern "C" void kernel_launch(void* const* d_in, const int* in_sizes, int n_in,
                              void* d_out, int out_size, void* d_ws, size_t ws_size,
                              hipStream_t stream)
{
    const float* src = (const float*)d_in[0];
    const int*   adj = (const int*)d_in[1];
    const float* Wq  = (const float*)d_in[2];
    const float* bq  = (const float*)d_in[3];
    const float* Wk  = (const float*)d_in[4];
    const float* bk  = (const float*)d_in[5];
    const float* Wv  = (const float*)d_in[6];
    const float* bv  = (const float*)d_in[7];
    const float* Wo  = (const float*)d_in[8];
    const float* bo  = (const float*)d_in[9];
    const float* W1  = (const float*)d_in[10];
    const float* b1  = (const float*)d_in[11];
    const float* W2  = (const float*)d_in[12];
    const float* b2  = (const float*)d_in[13];
    const float* g1  = (const float*)d_in[14];
    const float* be1 = (const float*)d_in[15];
    const float* g2  = (const float*)d_in[16];
    const float* be2 = (const float*)d_in[17];
    float* out = (float*)d_out;

    char* wsb = (char*)d_ws;
    const size_t MB = (size_t)1 << 20;

    // workspace layout (42 MB with aliasing)
    unsigned char* adjsel = (unsigned char*)(wsb);          // [0,8) MB byte-pair adj
    short* qkv_bf = (short*)(wsb + 8 * MB);                 // [8,32): q,k planes + vT
    short* src_bf = (short*)(wsb + 32 * MB);                // [32,36)
    short* wqkvT  = (short*)(wsb + 36 * MB);                // 768 KB
    short* woT    = (short*)(wsb + 36 * MB + 768 * 1024);   // 128 KB
    short* w1T    = (short*)(wsb + 36 * MB + 896 * 1024);   // 512 KB
    short* w2T    = (short*)(wsb + 36 * MB + 1408 * 1024);  // 512 KB
    float* bpack  = (float*)(wsb + 36 * MB + 1920 * 1024);  // 12 KB
    short* heads_bf = (short*)(wsb + 38 * MB);              // [38,42)
    short* x_bf   = (short*)(wsb + 32 * MB);                // reuse src_bf (LN1 out)
    short* h1_bf  = (short*)(wsb + 16 * MB);                // reuse vT (dead post-attn)

    const int M = CB * CN;        // 8192
    dim3 blk(256);

    // prep: src cast, coalesced weight transposes, biases (2300 blocks)
    prep<<<dim3(2300), blk, 0, stream>>>(src, Wq, Wk, Wv, Wo, W1, W2,
        bq, bk, bv, bo, b1, b2, src_bf, wqkvT, woT, w1T, w2T, bpack);

    // fused QK + V^T projection (128x128 tiles) + sigma byte pack: 1280 blocks
    proj_kernel<<<dim3(1280), blk, 32768, stream>>>(
        src_bf, wqkvT, bpack, qkv_bf, adj, adjsel);

    // fused relational MFMA attention (R7 config: 128 rows/block, 512 blocks)
    attn_mfma<<<dim3(512), blk, 0, stream>>>(
        qkv_bf, qkv_bf + SZH, qkv_bf + 2 * SZH, adjsel, heads_bf);

    // O-projection + bias + residual(src fp32) + LN1 -> x_bf bf16 only
    gemm_ln32<false, true, false><<<dim3(M / 32), blk, 0, stream>>>(
        heads_bf, woT, bpack + 1536, src, g1, be1, nullptr, x_bf, CD);

    // FFN1 (128x128 tiles): 512 blocks
    gemm_mfma<128, 128, MODE_FFN1><<<dim3(M / 128, CFF / 128), blk, 32768, stream>>>(
        x_bf, w1T, bpack + 1792, h1_bf, M, CD, CFF);

    // FFN2 + bias + residual(x_bf bf16) + LN2 -> out fp32
    gemm_ln32<true, false, true><<<dim3(M / 32), blk, 0, stream>>>(
        h1_bf, w2T, bpack + 2816, x_bf, g2, be2, out, nullptr, CFF);
}

// Round 11
// 209.423 us; speedup vs baseline: 1.0363x; 1.0308x over previous
//
#include <hip/hip_runtime.h>
#include <hip/hip_bf16.h>
#include <cmath>

// Problem constants (fixed by the reference)
constexpr int CB  = 8;     // batch
constexpr int CN  = 1024;  // sequence length
constexpr int CD  = 256;   // model dim
constexpr int CH  = 8;     // heads
constexpr int CDH = 32;    // head dim
constexpr int CR  = 4;     // relation types (adj value 4 = none)
constexpr int CFF = 1024;  // ffn dim
constexpr float CEPS = 1e-5f;
constexpr float CS = 0.25503480f;   // (1/sqrt(32)) * log2(e), folded into Q
constexpr size_t SZH = (size_t)CB * CH * CN * CDH;  // 2M: one head-plane

#define MODE_QK    0   // scatter bf16 q/k head-major planes, +bias (cols 0..511)
#define MODE_FFN1  2   // +bias, tanh-gelu -> bf16
#define MODE_VT    4   // V^T gemm (A=weight rows, B=src rows): sigma column store

typedef float v4f __attribute__((ext_vector_type(4)));
typedef short v8s __attribute__((ext_vector_type(8)));

static __device__ __forceinline__ short f2bf(float f) {
    unsigned u = __builtin_bit_cast(unsigned, f);
    u += 0x7fff + ((u >> 16) & 1);          // round-to-nearest-even
    return (short)(u >> 16);
}
static __device__ __forceinline__ float bf2f(short s) {
    unsigned u = ((unsigned)(unsigned short)s) << 16;
    return __builtin_bit_cast(float, u);
}
static __device__ __forceinline__ unsigned cvtpk_bf16(float lo, float hi) {
    unsigned r;
    asm("v_cvt_pk_bf16_f32 %0, %1, %2" : "=v"(r) : "v"(lo), "v"(hi));
    return r;
}

static __device__ __forceinline__ void async_copy16(const void* g, void* l) {
    __builtin_amdgcn_global_load_lds(
        (const __attribute__((address_space(1))) void*)g,
        (__attribute__((address_space(3))) void*)l, 16, 0, 0);
}

// PV k-order permutation sigma(j): c[5]=j[4], c[4:3]=j[3:2], c[2]=j[5],
// c[1:0]=j[1:0].  With swapped QK^T (sacc = mfma(K,Q)), lane (quad,l15)
// holds P[i=l15][j=16jb+4quad+rr], and sigma maps those 16 j's exactly onto
// PV A-operand k-slots {kb*32 + quad*8 + e} -> P never touches LDS.
// adjsel stores adj as BYTES in sigma pair order; at PV time the byte value
// itself is a v_perm selector into a one-hot 0xff table (v=4 -> zero operand).

// ---------------------------------------------------------------------------
// bf16 MFMA GEMM body (device fn, dynamic LDS): epilogue(A[M,K] @ Bw[N,K])
// BM x BN tile, 4 waves 2x2, BK=32 double-buffered 1-deep prefetch.
// ---------------------------------------------------------------------------
template<int BM, int BN, int MODE>
__device__ __forceinline__ void gemm_body(
    const short* __restrict__ A, const short* __restrict__ Bw,
    const float* __restrict__ biasv, void* __restrict__ dest,
    int M, int K, int Nw, int bx, int by, short* smem)
{
    constexpr int WTM = BM / 2, WTN = BN / 2;
    constexpr int TM = WTM / 16, TN = WTN / 16;
    short* As = smem;                    // [2][BM*32]
    short* Bs = smem + 2 * BM * 32;      // [2][BN*32]

    const int t    = threadIdx.x;
    const int lane = t & 63;
    const int w    = t >> 6;
    const int quad = lane >> 4, l15 = lane & 15;
    const int wm = w >> 1, wn = w & 1;
    const int m0 = bx * BM, n0 = by * BN;

    const int srow = lane >> 2;
    const int scol = (lane & 3) * 8;

    v4f acc[TM][TN];
    #pragma unroll
    for (int i = 0; i < TM; ++i)
        #pragma unroll
        for (int j = 0; j < TN; ++j) acc[i][j] = (v4f){0.f, 0.f, 0.f, 0.f};

    const int NK = K >> 5;

    auto stage = [&](int buf, int kt) {
        #pragma unroll
        for (int u = 0; u < BM / 64; ++u) {
            const int e0 = (w * (BM / 64) + u) * 512;
            const int row = (e0 >> 5) + srow;
            async_copy16(A + (size_t)(m0 + row) * K + kt + scol,
                         &As[buf * BM * 32 + e0]);
        }
        #pragma unroll
        for (int u = 0; u < BN / 64; ++u) {
            const int e0 = (w * (BN / 64) + u) * 512;
            const int row = (e0 >> 5) + srow;
            async_copy16(Bw + (size_t)(n0 + row) * K + kt + scol,
                         &Bs[buf * BN * 32 + e0]);
        }
    };

    stage(0, 0);

    for (int it = 0; it < NK; ++it) {
        __syncthreads();
        if (it + 1 < NK) stage((it + 1) & 1, (it + 1) << 5);

        const int buf = it & 1;
        v8s af[TM], bfr[TN];
        #pragma unroll
        for (int i = 0; i < TM; ++i)
            af[i] = *(const v8s*)&As[buf * BM * 32 +
                                     (wm * WTM + i * 16 + l15) * 32 + quad * 8];
        #pragma unroll
        for (int j = 0; j < TN; ++j)
            bfr[j] = *(const v8s*)&Bs[buf * BN * 32 +
                                      (wn * WTN + j * 16 + l15) * 32 + quad * 8];
        #pragma unroll
        for (int i = 0; i < TM; ++i)
            #pragma unroll
            for (int j = 0; j < TN; ++j)
                acc[i][j] = __builtin_amdgcn_mfma_f32_16x16x32_bf16(
                    af[i], bfr[j], acc[i][j], 0, 0, 0);
    }

    #pragma unroll
    for (int i = 0; i < TM; ++i) {
        #pragma unroll
        for (int j = 0; j < TN; ++j) {
            const int mb = m0 + wm * WTM + i * 16 + quad * 4;   // row of rr=0
            const int n  = n0 + wn * WTN + j * 16 + l15;
            float vals[4];
            if (MODE == MODE_VT) {
                #pragma unroll
                for (int rr = 0; rr < 4; ++rr) vals[rr] = acc[i][j][rr] + biasv[mb + rr];
            } else {
                #pragma unroll
                for (int rr = 0; rr < 4; ++rr) vals[rr] = acc[i][j][rr] + biasv[n];
            }

            if (MODE == MODE_QK) {
                // fold softmax scale into Q (q-plane blocks have n0 < 256)
                if (n0 < 256) {
                    #pragma unroll
                    for (int rr = 0; rr < 4; ++rr) vals[rr] *= CS;
                }
                const int b = mb >> 10, ii0 = mb & 1023;
                const int plane = n >> 8, nn = n & 255;
                const int h = nn >> 5, d = nn & 31;
                #pragma unroll
                for (int rr = 0; rr < 4; ++rr)
                    ((short*)dest)[(size_t)plane * SZH +
                        (((size_t)(b * CH + h)) * CN + ii0 + rr) * CDH + d] =
                        f2bf(vals[rr]);
            } else if (MODE == MODE_VT) {
                // sigma column permutation within each 64-token tile (see top)
                const int b = n >> 10, ii = n & 1023;
                const int jj = ii & 63;
                const int cc = (((jj >> 4) & 1) << 5) | (((jj >> 2) & 3) << 3) |
                               (((jj >> 5) & 1) << 2) | (jj & 3);
                const int iip = (ii & ~63) | cc;
                #pragma unroll
                for (int rr = 0; rr < 4; ++rr) {
                    const int m = mb + rr;
                    const int r2 = m >> 8, hd = m & 255;
                    const int h = hd >> 5, d = hd & 31;
                    ((short*)dest)[2 * SZH +
                        (((size_t)(r2 * 64 + b * CH + h)) * CDH + d) * CN + iip] =
                        f2bf(vals[rr]);
                }
            } else { // MODE_FFN1: tanh-gelu -> bf16 (x*E/(E+1))
                #pragma unroll
                for (int rr = 0; rr < 4; ++rr) {
                    const size_t idx = (size_t)(mb + rr) * Nw + n;
                    const float xx = vals[rr];
                    const float E = exp2f(2.302217f * (xx + 0.044715f * xx * xx * xx));
                    ((short*)dest)[idx] = f2bf(xx * E / (E + 1.f));
                }
            }
        }
    }
}

template<int BM, int BN, int MODE>
__global__ __launch_bounds__(256)
void gemm_mfma(const short* __restrict__ A, const short* __restrict__ Bw,
               const float* __restrict__ biasv, void* __restrict__ dest,
               int M, int K, int Nw)
{
    extern __shared__ short smem[];
    gemm_body<BM, BN, MODE>(A, Bw, biasv, dest, M, K, Nw,
                            blockIdx.x, blockIdx.y, smem);
}

// ---------------------------------------------------------------------------
// Fused projection dispatch (128x128 m97-style tiles):
//   blocks 0..255   = QK  (8192x512, K=256)
//   blocks 256..767 = V^T (1024x8192, K=256)
//   blocks 768..1279= adj int32 -> BYTE-pair pack in sigma order (adjsel)
// ---------------------------------------------------------------------------
__global__ __launch_bounds__(256)
void proj_kernel(const short* __restrict__ src_bf, const short* __restrict__ wqkvT,
                 const float* __restrict__ bpack, short* __restrict__ qkv,
                 const int* __restrict__ adj, unsigned char* __restrict__ adjsel)
{
    extern __shared__ short smem[];
    const int g = blockIdx.x;
    if (g < 256) {
        gemm_body<128, 128, MODE_QK>(src_bf, wqkvT, bpack, qkv,
                                     8192, 256, 512, g >> 2, g & 3, smem);
    } else if (g < 768) {
        const int h2 = g - 256;
        gemm_body<128, 128, MODE_VT>(wqkvT + 512 * 256, src_bf, bpack + 512,
                                     qkv, 1024, 256, 8192, h2 & 7, h2 >> 3, smem);
    } else {
        // sigma-order byte pack: int2 (row, dwi) holds adj bytes for the 8 j's
        // j0+{0..3}, j0+32+{0..3} with j0 = T*64 + (kq&3)*4 + (kq>>2)*16,
        // T = dwi>>3, kq = dwi&7  (kq = kb*4 + quad).
        const int nout = CB * CN * CN / 8;           // 1M int2 (8 j's each)
        for (int i = (g - 768) * 256 + threadIdx.x; i < nout; i += 512 * 256) {
            const int dwi = i & 127;
            const int row = i >> 7;
            const int T   = dwi >> 3, kq = dwi & 7;
            const int j0  = T * 64 + (kq & 3) * 4 + (kq >> 2) * 16;
            const int* p = adj + (size_t)row * CN + j0;
            const int4 q0 = *(const int4*)(p);
            const int4 q1 = *(const int4*)(p + 32);
            int2 o;
            o.x = (q0.x & 0xff) | ((q0.y & 0xff) << 8) |
                  ((q0.z & 0xff) << 16) | ((q0.w & 0xff) << 24);
            o.y = (q1.x & 0xff) | ((q1.y & 0xff) << 8) |
                  ((q1.z & 0xff) << 16) | ((q1.w & 0xff) << 24);
            ((int2*)adjsel)[i] = o;
        }
    }
}

// ---------------------------------------------------------------------------
// FUSED GEMM + bias + residual + LayerNorm, BM=16, BK=64 (half the barriers
// of BK=32; 8 MFMA per wave between barriers).  Granule-XOR swizzle on the
// 128B-stride LDS rows (source-side, linear dest) -> conflict-light reads.
// OUTF: write fp32 result; OUTB: write bf16 result; ADDBF: residual is bf16.
// ---------------------------------------------------------------------------
template<bool OUTF, bool OUTB, bool ADDBF>
__global__ __launch_bounds__(256)
void gemm_ln32(const short* __restrict__ A, const short* __restrict__ Bw,
               const float* __restrict__ biasv, const void* __restrict__ addp,
               const float* __restrict__ gw, const float* __restrict__ be,
               float* __restrict__ outf, short* __restrict__ outb, int K)
{
    __shared__ short As[2][16 * 64];
    __shared__ short Bs[2][256 * 64];
    __shared__ float redS[16][4], redQ[16][4];

    const int t    = threadIdx.x;
    const int lane = t & 63;
    const int w    = t >> 6;          // wave -> column quarter (64 cols)
    const int quad = lane >> 4, l15 = lane & 15;
    const int m0   = blockIdx.x * 16;
    const int xsw  = l15 & 7;         // read-side granule XOR

    v4f acc[4];
    #pragma unroll
    for (int j = 0; j < 4; ++j) acc[j] = (v4f){0.f, 0.f, 0.f, 0.f};

    const int NK = K >> 6;

    auto stage = [&](int buf, int kt) {
        if (t < 128) {   // A: 16 rows x 64 cols = 128 granules
            const int row = t >> 3, gc = t & 7;
            async_copy16(A + (size_t)(m0 + row) * K + kt + ((gc ^ (row & 7)) * 8),
                         &As[buf][t * 8]);
        }
        #pragma unroll
        for (int u = 0; u < 8; ++u) {   // B: 256 rows x 64 cols = 2048 granules
            const int gl = t + 256 * u;
            const int row = gl >> 3, gc = gl & 7;
            async_copy16(Bw + (size_t)row * K + kt + ((gc ^ (row & 7)) * 8),
                         &Bs[buf][gl * 8]);
        }
    };

    stage(0, 0);

    for (int it = 0; it < NK; ++it) {
        __syncthreads();
        if (it + 1 < NK) stage((it + 1) & 1, (it + 1) << 6);

        const int buf = it & 1;
        #pragma unroll
        for (int half = 0; half < 2; ++half) {
            const int gr = (quad + 4 * half) ^ xsw;
            const v8s af = *(const v8s*)&As[buf][l15 * 64 + gr * 8];
            #pragma unroll
            for (int j = 0; j < 4; ++j) {
                const v8s bfr = *(const v8s*)&Bs[buf][(w * 64 + 16 * j + l15) * 64 + gr * 8];
                acc[j] = __builtin_amdgcn_mfma_f32_16x16x32_bf16(af, bfr, acc[j], 0, 0, 0);
            }
        }
    }

    float v[4][4];
    #pragma unroll
    for (int rr = 0; rr < 4; ++rr) {
        const int row = m0 + quad * 4 + rr;
        float s = 0.f, sq = 0.f;
        #pragma unroll
        for (int j = 0; j < 4; ++j) {
            const int n = w * 64 + 16 * j + l15;
            const size_t idx = (size_t)row * CD + n;
            const float addv = ADDBF ? bf2f(((const short*)addp)[idx])
                                     : ((const float*)addp)[idx];
            const float x = acc[j][rr] + biasv[n] + addv;
            v[rr][j] = x;
            s += x; sq += x * x;
        }
        #pragma unroll
        for (int off = 1; off < 16; off <<= 1) {
            s  += __shfl_xor(s, off);
            sq += __shfl_xor(sq, off);
        }
        if (l15 == 0) {
            redS[quad * 4 + rr][w] = s;
            redQ[quad * 4 + rr][w] = sq;
        }
    }
    __syncthreads();

    #pragma unroll
    for (int rr = 0; rr < 4; ++rr) {
        const int r16 = quad * 4 + rr;
        const int row = m0 + r16;
        const float s  = (redS[r16][0] + redS[r16][1]) + (redS[r16][2] + redS[r16][3]);
        const float sq = (redQ[r16][0] + redQ[r16][1]) + (redQ[r16][2] + redQ[r16][3]);
        const float mean = s * (1.f / CD);
        const float var  = sq * (1.f / CD) - mean * mean;
        const float rstd = rsqrtf(var + CEPS);
        #pragma unroll
        for (int j = 0; j < 4; ++j) {
            const int n = w * 64 + 16 * j + l15;
            const float y = (v[rr][j] - mean) * rstd * gw[n] + be[n];
            if (OUTF) outf[(size_t)row * CD + n] = y;
            if (OUTB) outb[(size_t)row * CD + n] = f2bf(y);
        }
    }
}

// ---------------------------------------------------------------------------
// Prep: src->bf16, weight transposes via 64x64 LDS tiles, biases packed.
// ---------------------------------------------------------------------------
__global__ __launch_bounds__(256)
void prep(const float* __restrict__ src,
          const float* __restrict__ Wq, const float* __restrict__ Wk,
          const float* __restrict__ Wv, const float* __restrict__ Wo,
          const float* __restrict__ W1, const float* __restrict__ W2,
          const float* __restrict__ bq, const float* __restrict__ bk,
          const float* __restrict__ bv, const float* __restrict__ bo,
          const float* __restrict__ b1, const float* __restrict__ b2,
          short* __restrict__ src_bf,
          short* __restrict__ wqkvT, short* __restrict__ woT,
          short* __restrict__ w1T, short* __restrict__ w2T,
          float* __restrict__ bpack)
{
    __shared__ float tile[64][65];
    const int bx = blockIdx.x, t = threadIdx.x;
    if (bx < 2048) {                                   // src cast: 512K float4
        const int i = bx * 256 + t;
        const float4 v = ((const float4*)src)[i];
        short4 o;
        o.x = f2bf(v.x); o.y = f2bf(v.y); o.z = f2bf(v.z); o.w = f2bf(v.w);
        ((short4*)src_bf)[i] = o;
    } else if (bx < 2288) {                            // weight transposes
        const int tt = bx - 2048;
        const float* S; short* D;
        int Sstride, Dstride, k0, srccol, dstrow;
        if (tt < 96) {                                 // wqkv: 24x4 tiles
            const int tk = tt & 3, tn = tt >> 2;
            const int ng = tn * 64;
            Sstride = 256; Dstride = 256; k0 = tk * 64;
            dstrow = tn * 64; D = wqkvT;
            if (ng < 256)      { S = Wq; srccol = ng; }
            else if (ng < 512) { S = Wk; srccol = ng - 256; }
            else { const int r = (ng - 512) >> 8;
                   S = Wv + (size_t)r * 65536; srccol = (ng - 512) & 255; }
        } else if (tt < 112) {                         // wo: 4x4
            const int u = tt - 96, tk = u & 3, tn = u >> 2;
            S = Wo; Sstride = 256; D = woT; Dstride = 256;
            k0 = tk * 64; srccol = tn * 64; dstrow = tn * 64;
        } else if (tt < 176) {                         // w1: 16x4
            const int u = tt - 112, tk = u & 3, tn = u >> 2;
            S = W1; Sstride = 1024; D = w1T; Dstride = 256;
            k0 = tk * 64; srccol = tn * 64; dstrow = tn * 64;
        } else {                                       // w2: 4x16
            const int u = tt - 176, tk = u & 15, tn = u >> 4;
            S = W2; Sstride = 256; D = w2T; Dstride = 1024;
            k0 = tk * 64; srccol = tn * 64; dstrow = tn * 64;
        }
        #pragma unroll
        for (int u2 = 0; u2 < 4; ++u2) {               // coalesced read
            const int kl = (t >> 4) + u2 * 16;
            const int nl = (t & 15) * 4;
            const float4 v = *(const float4*)&S[(size_t)(k0 + kl) * Sstride + srccol + nl];
            tile[kl][nl + 0] = v.x; tile[kl][nl + 1] = v.y;
            tile[kl][nl + 2] = v.z; tile[kl][nl + 3] = v.w;
        }
        __syncthreads();
        #pragma unroll
        for (int u2 = 0; u2 < 4; ++u2) {               // coalesced write
            const int nl = (t >> 4) + u2 * 16;
            const int kl = (t & 15) * 4;
            short4 o;
            o.x = f2bf(tile[kl + 0][nl]); o.y = f2bf(tile[kl + 1][nl]);
            o.z = f2bf(tile[kl + 2][nl]); o.w = f2bf(tile[kl + 3][nl]);
            *(short4*)&D[(size_t)(dstrow + nl) * Dstride + k0 + kl] = o;
        }
    } else {                                           // biases: 3072
        const int idx = (bx - 2288) * 256 + t;
        float bvv;
        if (idx < 256)       bvv = bq[idx];
        else if (idx < 512)  bvv = bk[idx - 256];
        else if (idx < 1536) bvv = bv[idx - 512];
        else if (idx < 1792) bvv = bo[idx - 1536];
        else if (idx < 2816) bvv = b1[idx - 1792];
        else                 bvv = b2[idx - 2816];
        bpack[idx] = bvv;
    }
}

// ---------------------------------------------------------------------------
// Fused relational attention, 128 Q-rows per block (2 independent halves):
//  - each wave carries TWO dependency chains (hh=0,1) that interleave and
//    self-hide latency; K frags and V frags loaded ONCE, reused by both
//  - QK^T swapped (sacc = mfma(K,Q)) -> P lane-local; sigma k-order feeds PV
//  - byte-LUT masks via v_perm with adj byte as selector
//  - V^T staged by global_load_lds 2-deep ring; K/adjsel direct from L2
// One __syncthreads per j-tile.  XCD-aware 1D grid, 512 blocks (b = g & 7).
// ---------------------------------------------------------------------------
__global__ __launch_bounds__(256, 2)
void attn_mfma(const short* __restrict__ qg, const short* __restrict__ kg,
               const short* __restrict__ vt, const unsigned char* __restrict__ adjsel,
               short* __restrict__ outh)
{
    __shared__ __align__(16) short vtl[2][8192];  // [buf][r*2048 + d*64 + gc*8]

    const int t    = threadIdx.x;
    const int lane = t & 63;
    const int w    = t >> 6;          // wave 0..3
    const int quad = lane >> 4;
    const int l15  = lane & 15;
    const int g    = blockIdx.x;      // 1D grid, XCD-aware decode
    const int b    = g & 7;           // same XCD for whole batch
    const int h    = (g >> 3) & 7;
    const int i0   = (g >> 6) * 128;  // 8 tiles of 128 rows
    const int bhh  = b * CH + h;
    const size_t bh = (size_t)bhh;

    v8s qfrag[2];
    #pragma unroll
    for (int hh = 0; hh < 2; ++hh)
        qfrag[hh] = *(const v8s*)&qg[(bh * CN + i0 + 64 * hh + 16 * w + l15) * CDH + quad * 8];

    // V DMA sources: thread t stages granule gl = t + 256u; LDS granule
    // (r,d,gc) holds global granule gc^(d&7) of V^T row (r,d) in this j-tile.
    const short* vsrc[4];
    #pragma unroll
    for (int u = 0; u < 4; ++u) {
        const int gl = t + 256 * u;
        const int r = gl >> 8, d = (gl >> 3) & 31, gc = gl & 7;
        vsrc[u] = vt + ((size_t)(r * 64 + bhh) * CDH + d) * CN + (gc ^ (d & 7)) * 8;
    }
    // K direct: A-operand rows l15, k-chunk quad*8
    const short* kbase = kg + (bh * CN + l15) * CDH + quad * 8;
    // adjsel direct: row i0+64*hh+16w+l15, int2 (kb, quad) of the 64B slice
    const unsigned char* abase[2];
    #pragma unroll
    for (int hh = 0; hh < 2; ++hh)
        abase[hh] = adjsel + ((size_t)(b * CN) + i0 + 64 * hh + 16 * w + l15) * CN + quad * 8;

    v4f oacc[2][2][2];                 // [hh][cb][kb]
    #pragma unroll
    for (int hh = 0; hh < 2; ++hh)
        #pragma unroll
        for (int cb = 0; cb < 2; ++cb)
            #pragma unroll
            for (int kb = 0; kb < 2; ++kb) oacc[hh][cb][kb] = (v4f){0.f, 0.f, 0.f, 0.f};
    float plsum[2] = {0.f, 0.f};
    const int psw = (l15 & 7) * 8;         // vfrag granule XOR (pre-scaled)

    // ---- prologue: prefetch tile 0 ----
    #pragma unroll
    for (int u = 0; u < 4; ++u)
        async_copy16(vsrc[u], &vtl[0][(t + 256 * u) * 8]);
    v8s kpre[4];
    #pragma unroll
    for (int jb = 0; jb < 4; ++jb)
        kpre[jb] = *(const v8s*)(kbase + (16 * jb) * CDH);
    int2 apre[2][2];
    #pragma unroll
    for (int hh = 0; hh < 2; ++hh) {
        apre[hh][0] = *(const int2*)(abase[hh]);
        apre[hh][1] = *(const int2*)(abase[hh] + 32);
    }

    for (int jt = 0; jt < 16; ++jt) {
        __syncthreads();   // vtl[jt&1] staged; other buf free for prefetch
        const int p = jt & 1;

        // ---- QK swapped, both halves share kpre ----
        v4f sacc[2][4];
        #pragma unroll
        for (int hh = 0; hh < 2; ++hh)
            #pragma unroll
            for (int jb = 0; jb < 4; ++jb)
                sacc[hh][jb] = __builtin_amdgcn_mfma_f32_16x16x32_bf16(
                    kpre[jb], qfrag[hh], (v4f){0.f, 0.f, 0.f, 0.f}, 0, 0, 0);

        // ---- issue prefetches for tile jt+1 (wrap harmless on last iter) ----
        int2 aa[2][2];
        #pragma unroll
        for (int hh = 0; hh < 2; ++hh) {
            aa[hh][0] = apre[hh][0];
            aa[hh][1] = apre[hh][1];
        }
        const int jn = (jt + 1) & 15;
        #pragma unroll
        for (int u = 0; u < 4; ++u)
            async_copy16(vsrc[u] + jn * 64, &vtl[p ^ 1][(t + 256 * u) * 8]);
        #pragma unroll
        for (int jb = 0; jb < 4; ++jb)
            kpre[jb] = *(const v8s*)(kbase + (jn * 64 + 16 * jb) * CDH);
        #pragma unroll
        for (int hh = 0; hh < 2; ++hh) {
            apre[hh][0] = *(const int2*)(abase[hh] + jn * 64);
            apre[hh][1] = *(const int2*)(abase[hh] + jn * 64 + 32);
        }

        // ---- softmax numerators, both halves, all in registers ----
        float pv[2][4][4];   // [hh][jb][rr] = P[i=l15][j=16jb+4quad+rr]
        #pragma unroll
        for (int hh = 0; hh < 2; ++hh) {
            #pragma unroll
            for (int jb = 0; jb < 4; ++jb)
                #pragma unroll
                for (int rr = 0; rr < 4; ++rr) pv[hh][jb][rr] = exp2f(sacc[hh][jb][rr]);
            plsum[hh] += ((pv[hh][0][0] + pv[hh][0][1]) + (pv[hh][0][2] + pv[hh][0][3]))
                       + ((pv[hh][1][0] + pv[hh][1][1]) + (pv[hh][1][2] + pv[hh][1][3]))
                       + ((pv[hh][2][0] + pv[hh][2][1]) + (pv[hh][2][2] + pv[hh][2][3]))
                       + ((pv[hh][3][0] + pv[hh][3][1]) + (pv[hh][3][2] + pv[hh][3][3]));
        }

        // ---- PV: vf loaded once per kb, reused by both halves ----
        #pragma unroll
        for (int kb = 0; kb < 2; ++kb) {
            v8s vf[4][2];
            #pragma unroll
            for (int r = 0; r < 4; ++r)
                #pragma unroll
                for (int cb = 0; cb < 2; ++cb)
                    vf[r][cb] = *(const v8s*)&vtl[p][r * 2048 +
                        (16 * cb + l15) * 64 + (((4 * kb + quad) * 8) ^ psw)];

            #pragma unroll
            for (int hh = 0; hh < 2; ++hh) {
                // A-operand dwords: e = {0..7} = rr of jb=kb then rr of jb=kb+2
                const unsigned P[4] = {
                    cvtpk_bf16(pv[hh][kb][0],     pv[hh][kb][1]),
                    cvtpk_bf16(pv[hh][kb][2],     pv[hh][kb][3]),
                    cvtpk_bf16(pv[hh][kb + 2][0], pv[hh][kb + 2][1]),
                    cvtpk_bf16(pv[hh][kb + 2][2], pv[hh][kb + 2][3])};
                const int2 a2 = aa[hh][kb];
                // D[u] = [v0,v0,v1,v1] bytes for pair u
                const unsigned D[4] = {
                    __builtin_amdgcn_perm((unsigned)a2.x, (unsigned)a2.x, 0x01010000u),
                    __builtin_amdgcn_perm((unsigned)a2.x, (unsigned)a2.x, 0x03030202u),
                    __builtin_amdgcn_perm((unsigned)a2.y, (unsigned)a2.y, 0x01010000u),
                    __builtin_amdgcn_perm((unsigned)a2.y, (unsigned)a2.y, 0x03030202u)};
                unsigned pfm[4][4];
                #pragma unroll
                for (int r = 0; r < 4; ++r) {
                    const unsigned tb = 0xffu << (8 * r);   // one-hot byte table
                    #pragma unroll
                    for (int u = 0; u < 4; ++u)
                        pfm[r][u] = P[u] & __builtin_amdgcn_perm(0u, tb, D[u]);
                }
                __builtin_amdgcn_s_setprio(1);
                #pragma unroll
                for (int r = 0; r < 4; ++r) {
                    const v8s pfr = __builtin_bit_cast(v8s,
                        make_uint4(pfm[r][0], pfm[r][1], pfm[r][2], pfm[r][3]));
                    #pragma unroll
                    for (int cb = 0; cb < 2; ++cb)
                        oacc[hh][cb][kb] = __builtin_amdgcn_mfma_f32_16x16x32_bf16(
                            pfr, vf[r][cb], oacc[hh][cb][kb], 0, 0, 0);
                }
                __builtin_amdgcn_s_setprio(0);
            }
        }
    }

    // ---- epilogue: merge split accumulators, reduce plsum, normalize ----
    #pragma unroll
    for (int hh = 0; hh < 2; ++hh) {
        v4f ofin[2];
        ofin[0] = oacc[hh][0][0] + oacc[hh][0][1];
        ofin[1] = oacc[hh][1][0] + oacc[hh][1][1];
        float plF = plsum[hh];
        plF += __shfl_xor(plF, 16);
        plF += __shfl_xor(plF, 32);        // lane x: denom for row i=x&15
        #pragma unroll
        for (int rr = 0; rr < 4; ++rr) {
            const float inv = 1.f / __shfl(plF, quad * 4 + rr);
            const int row = i0 + 64 * hh + 16 * w + quad * 4 + rr;
            #pragma unroll
            for (int cb = 0; cb < 2; ++cb)
                outh[((size_t)b * CN + row) * CD + h * CDH + 16 * cb + l15] =
                    f2bf(ofin[cb][rr] * inv);
        }
    }
}

// ---------------------------------------------------------------------------
extern "C" void kernel_launch(void* const* d_in, const int* in_sizes, int n_in,
                              void* d_out, int out_size, void* d_ws, size_t ws_size,
                              hipStream_t stream)
{
    const float* src = (const float*)d_in[0];
    const int*   adj = (const int*)d_in[1];
    const float* Wq  = (const float*)d_in[2];
    const float* bq  = (const float*)d_in[3];
    const float* Wk  = (const float*)d_in[4];
    const float* bk  = (const float*)d_in[5];
    const float* Wv  = (const float*)d_in[6];
    const float* bv  = (const float*)d_in[7];
    const float* Wo  = (const float*)d_in[8];
    const float* bo  = (const float*)d_in[9];
    const float* W1  = (const float*)d_in[10];
    const float* b1  = (const float*)d_in[11];
    const float* W2  = (const float*)d_in[12];
    const float* b2  = (const float*)d_in[13];
    const float* g1  = (const float*)d_in[14];
    const float* be1 = (const float*)d_in[15];
    const float* g2  = (const float*)d_in[16];
    const float* be2 = (const float*)d_in[17];
    float* out = (float*)d_out;

    char* wsb = (char*)d_ws;
    const size_t MB = (size_t)1 << 20;

    // workspace layout (42 MB with aliasing)
    unsigned char* adjsel = (unsigned char*)(wsb);          // [0,8) MB byte-pair adj
    short* qkv_bf = (short*)(wsb + 8 * MB);                 // [8,32): q,k planes + vT
    short* src_bf = (short*)(wsb + 32 * MB);                // [32,36)
    short* wqkvT  = (short*)(wsb + 36 * MB);                // 768 KB
    short* woT    = (short*)(wsb + 36 * MB + 768 * 1024);   // 128 KB
    short* w1T    = (short*)(wsb + 36 * MB + 896 * 1024);   // 512 KB
    short* w2T    = (short*)(wsb + 36 * MB + 1408 * 1024);  // 512 KB
    float* bpack  = (float*)(wsb + 36 * MB + 1920 * 1024);  // 12 KB
    short* heads_bf = (short*)(wsb + 38 * MB);              // [38,42)
    short* x_bf   = (short*)(wsb + 32 * MB);                // reuse src_bf (LN1 out)
    short* h1_bf  = (short*)(wsb + 16 * MB);                // reuse vT (dead post-attn)

    const int M = CB * CN;        // 8192
    dim3 blk(256);

    // prep: src cast, coalesced weight transposes, biases (2300 blocks)
    prep<<<dim3(2300), blk, 0, stream>>>(src, Wq, Wk, Wv, Wo, W1, W2,
        bq, bk, bv, bo, b1, b2, src_bf, wqkvT, woT, w1T, w2T, bpack);

    // fused QK + V^T projection (128x128 tiles) + sigma byte pack: 1280 blocks
    proj_kernel<<<dim3(1280), blk, 32768, stream>>>(
        src_bf, wqkvT, bpack, qkv_bf, adj, adjsel);

    // fused relational MFMA attention (R7 config: 128 rows/block, 512 blocks)
    attn_mfma<<<dim3(512), blk, 0, stream>>>(
        qkv_bf, qkv_bf + SZH, qkv_bf + 2 * SZH, adjsel, heads_bf);

    // O-projection + bias + residual(src fp32) + LN1 -> x_bf bf16 only
    gemm_ln32<false, true, false><<<dim3(M / 16), blk, 0, stream>>>(
        heads_bf, woT, bpack + 1536, src, g1, be1, nullptr, x_bf, CD);

    // FFN1 (64x128 tiles, 1024 blocks = 4/CU for barrier-drain overlap)
    gemm_mfma<64, 128, MODE_FFN1><<<dim3(M / 64, CFF / 128), blk, 24576, stream>>>(
        x_bf, w1T, bpack + 1792, h1_bf, M, CD, CFF);

    // FFN2 + bias + residual(x_bf bf16) + LN2 -> out fp32
    gemm_ln32<true, false, true><<<dim3(M / 16), blk, 0, stream>>>(
        h1_bf, w2T, bpack + 2816, x_bf, g2, be2, out, nullptr, CFF);
}